// Round 1
// baseline (2037.220 us; speedup 1.0000x reference)
//
#include <hip/hip_runtime.h>
#include <hip/hip_bf16.h>
#include <math.h>

#define BATCH   4
#define SEQ     2044
#define DMODEL  512
#define DINNER  1024
#define NHEADS  16
#define HEADDIM 64
#define DSTATE  64
#define CONVDIM 1152
#define DINPROJ 2192
#define NROWS   (BATCH*SEQ)   // 8176

// ---------------- fp32 tiled GEMM: C[M,N] = A[M,K] @ B[K,N] ----------------
__global__ __launch_bounds__(256) void gemm_f32(const float* __restrict__ A,
                                                const float* __restrict__ B,
                                                float* __restrict__ C,
                                                int M, int N, int K) {
    __shared__ float As[16][65];   // As[k][m], padded to kill write conflicts
    __shared__ float Bs[16][64];   // Bs[k][n]
    const int tid = threadIdx.x;
    const int bm = blockIdx.x * 64;
    const int bn = blockIdx.y * 64;
    const int tx = tid & 15, ty = tid >> 4;

    float acc[4][4];
#pragma unroll
    for (int i = 0; i < 4; i++)
#pragma unroll
        for (int j = 0; j < 4; j++) acc[i][j] = 0.f;

    for (int kk = 0; kk < K; kk += 16) {
        // A tile: 64 rows x 16 k
#pragma unroll
        for (int i = 0; i < 4; i++) {
            int idx = tid + i * 256;
            int r = idx >> 4, c = idx & 15;
            int gm = bm + r;
            As[c][r] = (gm < M) ? A[(size_t)gm * K + kk + c] : 0.f;
        }
        // B tile: 16 k x 64 n
#pragma unroll
        for (int i = 0; i < 4; i++) {
            int idx = tid + i * 256;
            int r = idx >> 6, c = idx & 63;
            int gn = bn + c;
            Bs[r][c] = (gn < N) ? B[(size_t)(kk + r) * N + gn] : 0.f;
        }
        __syncthreads();
#pragma unroll
        for (int k = 0; k < 16; k++) {
            float a[4], bv[4];
#pragma unroll
            for (int i = 0; i < 4; i++) a[i] = As[k][ty * 4 + i];
#pragma unroll
            for (int j = 0; j < 4; j++) bv[j] = Bs[k][tx * 4 + j];
#pragma unroll
            for (int i = 0; i < 4; i++)
#pragma unroll
                for (int j = 0; j < 4; j++) acc[i][j] += a[i] * bv[j];
        }
        __syncthreads();
    }
#pragma unroll
    for (int i = 0; i < 4; i++) {
        int gm = bm + ty * 4 + i;
        if (gm >= M) continue;
#pragma unroll
        for (int j = 0; j < 4; j++) {
            int gn = bn + tx * 4 + j;
            if (gn < N) C[(size_t)gm * N + gn] = acc[i][j];
        }
    }
}

// -------- depthwise causal conv (k=4) + bias + SiLU over xBC columns --------
__global__ __launch_bounds__(256) void conv_silu_kernel(const float* __restrict__ zxbcdt,
                                                        const float* __restrict__ conv_w,
                                                        const float* __restrict__ conv_b,
                                                        float* __restrict__ convout) {
    int idx = blockIdx.x * 256 + threadIdx.x;
    if (idx >= NROWS * CONVDIM) return;
    int c = idx % CONVDIM;
    int m = idx / CONVDIM;
    int t = m % SEQ;
    float acc = conv_b[c];
#pragma unroll
    for (int k = 0; k < 4; k++) {
        int tt = t - 3 + k;
        if (tt >= 0)
            acc += zxbcdt[(size_t)(m - 3 + k) * DINPROJ + DINNER + c] * conv_w[c * 4 + k];
    }
    float s = acc / (1.f + expf(-acc));   // silu
    convout[(size_t)m * CONVDIM + c] = s;
}

// -------- dt = softplus(dt_raw + bias); decay = exp(dt * -exp(A_log)) --------
__global__ __launch_bounds__(256) void dt_kernel(const float* __restrict__ zxbcdt,
                                                 const float* __restrict__ dt_bias,
                                                 const float* __restrict__ A_log,
                                                 float* __restrict__ dtp,
                                                 float* __restrict__ decay) {
    int idx = blockIdx.x * 256 + threadIdx.x;
    if (idx >= NROWS * NHEADS) return;
    int h = idx & 15;
    int m = idx >> 4;
    float xv = zxbcdt[(size_t)m * DINPROJ + (DINNER + CONVDIM) + h] + dt_bias[h];
    float sp = (xv > 20.f) ? xv : log1pf(expf(xv));
    float A = -expf(A_log[h]);
    dtp[idx] = sp;
    decay[idx] = expf(sp * A);
}

// ---------------- selective scan: one block per (b, head) ----------------
// thread (p = tid>>2, nq = tid&3) owns h[p, nq*16 .. nq*16+15]
__global__ __launch_bounds__(256) void scan_kernel(const float* __restrict__ convout,
                                                   const float* __restrict__ dtp,
                                                   const float* __restrict__ decay,
                                                   const float* __restrict__ D_skip,
                                                   float* __restrict__ y) {
    const int bh = blockIdx.x;
    const int b = bh >> 4;
    const int hh = bh & 15;
    const int tid = threadIdx.x;
    const int p = tid >> 2, nq = tid & 3;

    __shared__ float sB[2][64], sC[2][64], sX[2][64], sS[2][2];

    float hs[16];
#pragma unroll
    for (int j = 0; j < 16; j++) hs[j] = 0.f;
    const float dsk = D_skip[hh];
    const size_t rowbase = (size_t)b * SEQ;

    // stage t = 0 into buffer 0
    {
        const float* row = convout + (rowbase + 0) * CONVDIM;
        if (tid < 64)       sB[0][tid]        = row[1024 + tid];
        else if (tid < 128) sC[0][tid - 64]   = row[1088 + (tid - 64)];
        else if (tid < 192) sX[0][tid - 128]  = row[hh * 64 + (tid - 128)];
        else if (tid == 192) sS[0][0] = decay[(rowbase + 0) * NHEADS + hh];
        else if (tid == 193) sS[0][1] = dtp[(rowbase + 0) * NHEADS + hh];
    }
    __syncthreads();

    for (int t = 0; t < SEQ; t++) {
        const int cur = t & 1;
        // prefetch t+1 into the other buffer
        if (t + 1 < SEQ) {
            const int nxt = cur ^ 1;
            const float* row = convout + (rowbase + t + 1) * CONVDIM;
            if (tid < 64)       sB[nxt][tid]       = row[1024 + tid];
            else if (tid < 128) sC[nxt][tid - 64]  = row[1088 + (tid - 64)];
            else if (tid < 192) sX[nxt][tid - 128] = row[hh * 64 + (tid - 128)];
            else if (tid == 192) sS[nxt][0] = decay[(rowbase + t + 1) * NHEADS + hh];
            else if (tid == 193) sS[nxt][1] = dtp[(rowbase + t + 1) * NHEADS + hh];
        }
        const float dec = sS[cur][0];
        const float dtv = sS[cur][1];
        const float xp = sX[cur][p];
        const float dtx = dtv * xp;
        float yacc = 0.f;
#pragma unroll
        for (int j = 0; j < 16; j++) {
            float Bv = sB[cur][nq * 16 + j];
            float Cv = sC[cur][nq * 16 + j];
            hs[j] = dec * hs[j] + dtx * Bv;
            yacc += hs[j] * Cv;
        }
        yacc += __shfl_xor(yacc, 1);
        yacc += __shfl_xor(yacc, 2);
        if (nq == 0)
            y[(rowbase + t) * DINNER + hh * 64 + p] = yacc + dsk * xp;
        __syncthreads();
    }
}

// ---------------- gate with silu(z) + RMSNorm (in place on y) ----------------
__global__ __launch_bounds__(256) void gate_rmsnorm_kernel(float* __restrict__ y,
                                                           const float* __restrict__ zxbcdt,
                                                           const float* __restrict__ norm_w) {
    const int m = blockIdx.x;
    const int tid = threadIdx.x;
    float vals[4];
    float ss = 0.f;
#pragma unroll
    for (int i = 0; i < 4; i++) {
        int c = tid + i * 256;
        float v = y[(size_t)m * DINNER + c];
        float z = zxbcdt[(size_t)m * DINPROJ + c];
        float g = v * (z / (1.f + expf(-z)));
        vals[i] = g;
        ss += g * g;
    }
#pragma unroll
    for (int mask = 1; mask < 64; mask <<= 1) ss += __shfl_xor(ss, mask);
    __shared__ float red[4];
    if ((tid & 63) == 0) red[tid >> 6] = ss;
    __syncthreads();
    float tot = red[0] + red[1] + red[2] + red[3];
    float scale = rsqrtf(tot / 1024.f + 1e-5f);
#pragma unroll
    for (int i = 0; i < 4; i++) {
        int c = tid + i * 256;
        y[(size_t)m * DINNER + c] = vals[i] * scale * norm_w[c];
    }
}

extern "C" void kernel_launch(void* const* d_in, const int* in_sizes, int n_in,
                              void* d_out, int out_size, void* d_ws, size_t ws_size,
                              hipStream_t stream) {
    const float* x          = (const float*)d_in[0];
    const float* in_proj_w  = (const float*)d_in[1];
    const float* conv_w     = (const float*)d_in[2];
    const float* conv_b     = (const float*)d_in[3];
    const float* dt_bias    = (const float*)d_in[4];
    const float* A_log      = (const float*)d_in[5];
    const float* D_skip     = (const float*)d_in[6];
    const float* norm_w     = (const float*)d_in[7];
    const float* out_proj_w = (const float*)d_in[8];
    float* out = (float*)d_out;

    float* ws = (float*)d_ws;
    float* zxbcdt  = ws;                                   // NROWS*2192
    float* convout = zxbcdt + (size_t)NROWS * DINPROJ;     // NROWS*1152
    float* dtpb    = convout + (size_t)NROWS * CONVDIM;    // NROWS*16
    float* decayb  = dtpb + (size_t)NROWS * NHEADS;        // NROWS*16
    float* ybuf    = decayb + (size_t)NROWS * NHEADS;      // NROWS*1024

    // K1: zxbcdt = x @ in_proj_w
    dim3 g1((NROWS + 63) / 64, (DINPROJ + 63) / 64);
    gemm_f32<<<g1, 256, 0, stream>>>(x, in_proj_w, zxbcdt, NROWS, DINPROJ, DMODEL);

    // K2: depthwise conv + silu
    int convtot = NROWS * CONVDIM;
    conv_silu_kernel<<<(convtot + 255) / 256, 256, 0, stream>>>(zxbcdt, conv_w, conv_b, convout);

    // K2b: dt/decay
    int dttot = NROWS * NHEADS;
    dt_kernel<<<(dttot + 255) / 256, 256, 0, stream>>>(zxbcdt, dt_bias, A_log, dtpb, decayb);

    // K3: selective scan
    scan_kernel<<<BATCH * NHEADS, 256, 0, stream>>>(convout, dtpb, decayb, D_skip, ybuf);

    // K4: gate + rmsnorm (in place on ybuf)
    gate_rmsnorm_kernel<<<NROWS, 256, 0, stream>>>(ybuf, zxbcdt, norm_w);

    // K5: out = ybuf @ out_proj_w
    dim3 g5((NROWS + 63) / 64, (DMODEL + 63) / 64);
    gemm_f32<<<g5, 256, 0, stream>>>(ybuf, out_proj_w, out, NROWS, DMODEL, DINNER);
}

// Round 2
// 1164.626 us; speedup vs baseline: 1.7492x; 1.7492x over previous
//
#include <hip/hip_runtime.h>
#include <hip/hip_bf16.h>
#include <math.h>

#define BATCH   4
#define SEQ     2044
#define DMODEL  512
#define DINNER  1024
#define NHEADS  16
#define HEADDIM 64
#define DSTATE  64
#define CONVDIM 1152
#define DINPROJ 2192
#define NROWS   (BATCH*SEQ)   // 8176
#define Q       64
#define NCHUNK  32            // ceil(2044/64)

// ---------------- fp32 tiled GEMM: C[M,N] = A[M,K] @ B[K,N] ----------------
__global__ __launch_bounds__(256) void gemm_f32(const float* __restrict__ A,
                                                const float* __restrict__ B,
                                                float* __restrict__ C,
                                                int M, int N, int K) {
    __shared__ float As[16][65];
    __shared__ float Bs[16][64];
    const int tid = threadIdx.x;
    const int bm = blockIdx.x * 64;
    const int bn = blockIdx.y * 64;
    const int tx = tid & 15, ty = tid >> 4;

    float acc[4][4];
#pragma unroll
    for (int i = 0; i < 4; i++)
#pragma unroll
        for (int j = 0; j < 4; j++) acc[i][j] = 0.f;

    for (int kk = 0; kk < K; kk += 16) {
#pragma unroll
        for (int i = 0; i < 4; i++) {
            int idx = tid + i * 256;
            int r = idx >> 4, c = idx & 15;
            int gm = bm + r;
            As[c][r] = (gm < M) ? A[(size_t)gm * K + kk + c] : 0.f;
        }
#pragma unroll
        for (int i = 0; i < 4; i++) {
            int idx = tid + i * 256;
            int r = idx >> 6, c = idx & 63;
            int gn = bn + c;
            Bs[r][c] = (gn < N) ? B[(size_t)(kk + r) * N + gn] : 0.f;
        }
        __syncthreads();
#pragma unroll
        for (int k = 0; k < 16; k++) {
            float a[4], bv[4];
#pragma unroll
            for (int i = 0; i < 4; i++) a[i] = As[k][ty * 4 + i];
#pragma unroll
            for (int j = 0; j < 4; j++) bv[j] = Bs[k][tx * 4 + j];
#pragma unroll
            for (int i = 0; i < 4; i++)
#pragma unroll
                for (int j = 0; j < 4; j++) acc[i][j] += a[i] * bv[j];
        }
        __syncthreads();
    }
#pragma unroll
    for (int i = 0; i < 4; i++) {
        int gm = bm + ty * 4 + i;
        if (gm >= M) continue;
#pragma unroll
        for (int j = 0; j < 4; j++) {
            int gn = bn + tx * 4 + j;
            if (gn < N) C[(size_t)gm * N + gn] = acc[i][j];
        }
    }
}

// -------- depthwise causal conv (k=4) + bias + SiLU over xBC columns --------
__global__ __launch_bounds__(256) void conv_silu_kernel(const float* __restrict__ zxbcdt,
                                                        const float* __restrict__ conv_w,
                                                        const float* __restrict__ conv_b,
                                                        float* __restrict__ convout) {
    int idx = blockIdx.x * 256 + threadIdx.x;
    if (idx >= NROWS * CONVDIM) return;
    int c = idx % CONVDIM;
    int m = idx / CONVDIM;
    int t = m % SEQ;
    float acc = conv_b[c];
#pragma unroll
    for (int k = 0; k < 4; k++) {
        int tt = t - 3 + k;
        if (tt >= 0)
            acc += zxbcdt[(size_t)(m - 3 + k) * DINPROJ + DINNER + c] * conv_w[c * 4 + k];
    }
    float s = acc / (1.f + expf(-acc));
    convout[(size_t)m * CONVDIM + c] = s;
}

// ---- dt = softplus(dt_raw + bias); la = dt * A (log of per-step decay) ----
__global__ __launch_bounds__(256) void dt_kernel(const float* __restrict__ zxbcdt,
                                                 const float* __restrict__ dt_bias,
                                                 const float* __restrict__ A_log,
                                                 float* __restrict__ dtp,
                                                 float* __restrict__ la) {
    int idx = blockIdx.x * 256 + threadIdx.x;
    if (idx >= NROWS * NHEADS) return;
    int h = idx & 15;
    int m = idx >> 4;
    float xv = zxbcdt[(size_t)m * DINPROJ + (DINNER + CONVDIM) + h] + dt_bias[h];
    float sp = (xv > 20.f) ? xv : log1pf(expf(xv));
    float A = -expf(A_log[h]);
    dtp[idx] = sp;
    la[idx] = sp * A;
}

// ------------- Phase A: per-(b,chunk,head) intra-chunk + chunk state -------------
// block = (b*NCHUNK + c)*NHEADS + h, 256 threads
__global__ __launch_bounds__(256) void chunk_intra_kernel(
    const float* __restrict__ convout,
    const float* __restrict__ dtp,
    const float* __restrict__ la,
    const float* __restrict__ D_skip,
    float* __restrict__ ybuf,
    float* __restrict__ Sbuf,
    float* __restrict__ atot,
    float* __restrict__ cumexp)
{
    const int blk = blockIdx.x;
    const int h  = blk & 15;
    const int bc = blk >> 4;
    const int c  = bc & (NCHUNK - 1);
    const int b  = bc >> 5;
    const int t0 = c * Q;
    const int len = min(Q, SEQ - t0);
    const int tid = threadIdx.x;
    const size_t rowbase = (size_t)b * SEQ + t0;

    __shared__ float Bs[Q][65], Cs[Q][65], Xs[Q][65];
    __shared__ float cumS[Q], wS[Q], sdtS[Q];

    // step 1: within-chunk inclusive cumsum of log-decay (wave 0, lane t)
    if (tid < Q) {
        int t = tid;
        float lav = 0.f, dtv = 0.f;
        if (t < len) {
            lav = la[(rowbase + t) * NHEADS + h];
            dtv = dtp[(rowbase + t) * NHEADS + h];
        }
        float v = lav;
#pragma unroll
        for (int off = 1; off < 64; off <<= 1) {
            float nb = __shfl_up(v, off);
            if (tid >= off) v += nb;
        }
        cumS[t] = v;
        sdtS[t] = dtv;
        if (t < len) cumexp[(rowbase + t) * NHEADS + h] = expf(v);
    }
    __syncthreads();
    const float cumlast = cumS[Q - 1];
    if (tid < Q) wS[tid] = expf(cumlast - cumS[tid]) * sdtS[tid];

    // load tiles: B, C, raw x (head slice)
#pragma unroll
    for (int k = 0; k < 16; k++) {
        int idx = tid + k * 256;
        int t = idx >> 6, n = idx & 63;
        float bv = 0.f, cv = 0.f, xv = 0.f;
        if (t < len) {
            const float* row = convout + (rowbase + t) * CONVDIM;
            bv = row[1024 + n];
            cv = row[1088 + n];
            xv = row[h * 64 + n];
        }
        Bs[t][n] = bv; Cs[t][n] = cv; Xs[t][n] = xv;
    }
    __syncthreads();

    // E[t][s] = (C_t . B_s) * exp(cum_t - cum_s) * dt_s, masked to s<=t
    float Ereg[16];
    const int lane = tid & 63;
    const int tg = tid >> 6;  // 0..3
#pragma unroll
    for (int i = 0; i < 16; i++) {
        int t = tg * 16 + i;
        float acc = 0.f;
#pragma unroll
        for (int n = 0; n < 64; n++) acc += Cs[t][n] * Bs[lane][n];
        float val = 0.f;
        if (lane <= t) val = acc * expf(cumS[t] - cumS[lane]) * sdtS[lane];
        Ereg[i] = val;
    }
    __syncthreads();
    // overwrite Cs with masked-decayed E
#pragma unroll
    for (int i = 0; i < 16; i++) Cs[tg * 16 + i][lane] = Ereg[i];
    __syncthreads();

    // Y_intra[t][p] = sum_{s<=t} E[t][s] * x_s[p]  + D*x_t[p]
    const float dsk = D_skip[h];
#pragma unroll
    for (int i = 0; i < 16; i++) {
        int t = tg + 4 * i;
        float acc = dsk * Xs[t][lane];
        for (int s = 0; s <= t; s++) acc += Cs[t][s] * Xs[s][lane];
        if (t < len) ybuf[(rowbase + t) * DINNER + h * 64 + lane] = acc;
    }

    // S[p][n] = sum_s w_s * x_s[p] * B_s[n]   (chunk's contribution to state)
    const size_t sbase = (size_t)blk * 4096;
#pragma unroll
    for (int i = 0; i < 16; i++) {
        int p = tg + 4 * i;
        float acc = 0.f;
#pragma unroll
        for (int s = 0; s < 64; s++) acc += wS[s] * Xs[s][p] * Bs[s][lane];
        Sbuf[sbase + p * 64 + lane] = acc;
    }
    if (tid == 0) atot[blk] = expf(cumlast);
}

// ------- Phase B: sequential scan over chunk states; Sbuf becomes Hprev -------
// block = b*NHEADS + h
__global__ __launch_bounds__(256) void chunk_state_scan_kernel(
    float* __restrict__ Sbuf, const float* __restrict__ atot)
{
    const int bh = blockIdx.x;
    const int b = bh >> 4, h = bh & 15;
    const int tid = threadIdx.x;
    float H[16];
#pragma unroll
    for (int j = 0; j < 16; j++) H[j] = 0.f;
    for (int c = 0; c < NCHUNK; c++) {
        int blk = (b * NCHUNK + c) * NHEADS + h;
        size_t base = (size_t)blk * 4096;
        float at = atot[blk];
#pragma unroll
        for (int j = 0; j < 16; j++) {
            size_t off = base + tid + j * 256;
            float sv = Sbuf[off];
            Sbuf[off] = H[j];                 // Hprev for chunk c
            H[j] = at * H[j] + sv;
        }
    }
}

// ------- Phase C: Y += exp(cum_t) * C_t @ Hprev^T -------
__global__ __launch_bounds__(256) void chunk_inter_kernel(
    const float* __restrict__ convout,
    const float* __restrict__ Hbuf,
    const float* __restrict__ cumexp,
    float* __restrict__ ybuf)
{
    const int blk = blockIdx.x;
    const int h  = blk & 15;
    const int bc = blk >> 4;
    const int c  = bc & (NCHUNK - 1);
    const int b  = bc >> 5;
    const int t0 = c * Q;
    const int len = min(Q, SEQ - t0);
    const int tid = threadIdx.x;
    const size_t rowbase = (size_t)b * SEQ + t0;

    __shared__ float Hs[64][65], Cs[Q][65];
    const size_t hbase = (size_t)blk * 4096;
#pragma unroll
    for (int k = 0; k < 16; k++) {
        int idx = tid + k * 256;
        int r = idx >> 6, n = idx & 63;
        Hs[r][n] = Hbuf[hbase + idx];
        float cv = 0.f;
        if (r < len) cv = convout[(rowbase + r) * CONVDIM + 1088 + n];
        Cs[r][n] = cv;
    }
    __syncthreads();
    const int lane = tid & 63;
    const int tg = tid >> 6;
#pragma unroll
    for (int i = 0; i < 16; i++) {
        int t = tg + 4 * i;
        if (t >= len) continue;
        float acc = 0.f;
#pragma unroll
        for (int n = 0; n < 64; n++) acc += Cs[t][n] * Hs[lane][n];
        size_t off = (rowbase + t) * DINNER + h * 64 + lane;
        ybuf[off] += acc * cumexp[(rowbase + t) * NHEADS + h];
    }
}

// ---------------- gate with silu(z) + RMSNorm (in place on y) ----------------
__global__ __launch_bounds__(256) void gate_rmsnorm_kernel(float* __restrict__ y,
                                                           const float* __restrict__ zxbcdt,
                                                           const float* __restrict__ norm_w) {
    const int m = blockIdx.x;
    const int tid = threadIdx.x;
    float vals[4];
    float ss = 0.f;
#pragma unroll
    for (int i = 0; i < 4; i++) {
        int c = tid + i * 256;
        float v = y[(size_t)m * DINNER + c];
        float z = zxbcdt[(size_t)m * DINPROJ + c];
        float g = v * (z / (1.f + expf(-z)));
        vals[i] = g;
        ss += g * g;
    }
#pragma unroll
    for (int mask = 1; mask < 64; mask <<= 1) ss += __shfl_xor(ss, mask);
    __shared__ float red[4];
    if ((tid & 63) == 0) red[tid >> 6] = ss;
    __syncthreads();
    float tot = red[0] + red[1] + red[2] + red[3];
    float scale = rsqrtf(tot / 1024.f + 1e-5f);
#pragma unroll
    for (int i = 0; i < 4; i++) {
        int c = tid + i * 256;
        y[(size_t)m * DINNER + c] = vals[i] * scale * norm_w[c];
    }
}

extern "C" void kernel_launch(void* const* d_in, const int* in_sizes, int n_in,
                              void* d_out, int out_size, void* d_ws, size_t ws_size,
                              hipStream_t stream) {
    const float* x          = (const float*)d_in[0];
    const float* in_proj_w  = (const float*)d_in[1];
    const float* conv_w     = (const float*)d_in[2];
    const float* conv_b     = (const float*)d_in[3];
    const float* dt_bias    = (const float*)d_in[4];
    const float* A_log      = (const float*)d_in[5];
    const float* D_skip     = (const float*)d_in[6];
    const float* norm_w     = (const float*)d_in[7];
    const float* out_proj_w = (const float*)d_in[8];
    float* out = (float*)d_out;

    float* ws = (float*)d_ws;
    float* zxbcdt  = ws;                                   // NROWS*2192
    float* convout = zxbcdt + (size_t)NROWS * DINPROJ;     // NROWS*1152
    float* dtpb    = convout + (size_t)NROWS * CONVDIM;    // NROWS*16
    float* lab     = dtpb + (size_t)NROWS * NHEADS;        // NROWS*16
    float* cumexpb = lab + (size_t)NROWS * NHEADS;         // NROWS*16
    float* ybuf    = cumexpb + (size_t)NROWS * NHEADS;     // NROWS*1024
    float* Sbuf    = ybuf + (size_t)NROWS * DINNER;        // 2048*4096
    float* atotb   = Sbuf + (size_t)BATCH * NCHUNK * NHEADS * 4096;  // 2048

    // K1: zxbcdt = x @ in_proj_w
    dim3 g1((NROWS + 63) / 64, (DINPROJ + 63) / 64);
    gemm_f32<<<g1, 256, 0, stream>>>(x, in_proj_w, zxbcdt, NROWS, DINPROJ, DMODEL);

    // K2: depthwise conv + silu
    int convtot = NROWS * CONVDIM;
    conv_silu_kernel<<<(convtot + 255) / 256, 256, 0, stream>>>(zxbcdt, conv_w, conv_b, convout);

    // K2b: dt / log-decay
    int dttot = NROWS * NHEADS;
    dt_kernel<<<(dttot + 255) / 256, 256, 0, stream>>>(zxbcdt, dt_bias, A_log, dtpb, lab);

    // K3a: intra-chunk + chunk states (parallel over 2048 chunk-tasks)
    chunk_intra_kernel<<<BATCH * NCHUNK * NHEADS, 256, 0, stream>>>(
        convout, dtpb, lab, D_skip, ybuf, Sbuf, atotb, cumexpb);

    // K3b: inter-chunk state recurrence (32 steps, in registers)
    chunk_state_scan_kernel<<<BATCH * NHEADS, 256, 0, stream>>>(Sbuf, atotb);

    // K3c: add inter-chunk contribution to Y
    chunk_inter_kernel<<<BATCH * NCHUNK * NHEADS, 256, 0, stream>>>(
        convout, Sbuf, cumexpb, ybuf);

    // K4: gate + rmsnorm (in place on ybuf)
    gate_rmsnorm_kernel<<<NROWS, 256, 0, stream>>>(ybuf, zxbcdt, norm_w);

    // K5: out = ybuf @ out_proj_w
    dim3 g5((NROWS + 63) / 64, (DMODEL + 63) / 64);
    gemm_f32<<<g5, 256, 0, stream>>>(ybuf, out_proj_w, out, NROWS, DMODEL, DINNER);
}

// Round 4
// 263.029 us; speedup vs baseline: 7.7452x; 4.4277x over previous
//
#include <hip/hip_runtime.h>
#include <hip/hip_bf16.h>
#include <math.h>
#include <string.h>

#define BATCH   4
#define SEQ     2044
#define DMODEL  512
#define DINNER  1024
#define NHEADS  16
#define HEADDIM 64
#define DSTATE  64
#define CONVDIM 1152
#define DINPROJ 2192
#define ZW      2176          // stored width of zxbcdt (z + xBC, dt cols dropped)
#define NROWS   (BATCH*SEQ)   // 8176
#define Q       64
#define NCHUNK  32

typedef __attribute__((ext_vector_type(8))) short bf16x8;
typedef __attribute__((ext_vector_type(4))) float f32x4;

#define MFMA(a,b,c) __builtin_amdgcn_mfma_f32_16x16x32_bf16((a),(b),(c),0,0,0)

__device__ inline short f2bf(float f) {
    __hip_bfloat16 h = __float2bfloat16(f);
    short s; memcpy(&s, &h, 2); return s;
}
__device__ inline float bf2f(short s) {
    unsigned u = ((unsigned)(unsigned short)s) << 16;
    float f; memcpy(&f, &u, 4); return f;
}

// ---------------- elementwise fp32 -> bf16 convert (8/thread) ----------------
__global__ __launch_bounds__(256) void convert_bf16_kernel(const float* __restrict__ in,
                                                           short* __restrict__ out, int n8) {
    int i = blockIdx.x * 256 + threadIdx.x;
    if (i >= n8) return;
    float4 v0 = *((const float4*)in + i * 2);
    float4 v1 = *((const float4*)in + i * 2 + 1);
    short t[8];
    t[0]=f2bf(v0.x); t[1]=f2bf(v0.y); t[2]=f2bf(v0.z); t[3]=f2bf(v0.w);
    t[4]=f2bf(v1.x); t[5]=f2bf(v1.y); t[6]=f2bf(v1.z); t[7]=f2bf(v1.w);
    *((bf16x8*)out + i) = *(const bf16x8*)t;
}

// ------- transpose + convert: in fp32 [R][*ldi*] -> out bf16 [Cc][R] -------
// ldi = actual row stride of `in` (may exceed Cc when slicing columns)
__global__ __launch_bounds__(256) void transpose_cvt_kernel(const float* __restrict__ in,
                                                            short* __restrict__ out,
                                                            int R, int Cc, int ldi) {
    __shared__ float tile[64][65];
    const int bx = blockIdx.x * 64;   // C offset (output row)
    const int by = blockIdx.y * 64;   // R offset
    const int tid = threadIdx.x;
#pragma unroll
    for (int i = 0; i < 16; i++) {
        int idx = tid + i * 256; int r = idx >> 6, c = idx & 63;
        float v = 0.f;
        if (by + r < R && bx + c < Cc) v = in[(size_t)(by + r) * ldi + bx + c];
        tile[r][c] = v;
    }
    __syncthreads();
#pragma unroll
    for (int i = 0; i < 16; i++) {
        int idx = tid + i * 256; int c = idx >> 6, r = idx & 63;
        if (bx + c < Cc && by + r < R)
            out[(size_t)(bx + c) * R + by + r] = f2bf(tile[r][c]);
    }
}

// -------- bf16 MFMA GEMM: A[M][K] bf16, Bt[N][K] bf16 -> C[M][N] fp32 --------
// 64x64 tile, 4 waves, wave w owns rows [w*16, w*16+16)
__global__ __launch_bounds__(256) void gemm_bf16(const short* __restrict__ A,
                                                 const short* __restrict__ Bt,
                                                 float* __restrict__ C,
                                                 int M, int N, int K) {
    __shared__ short As[64][72];
    __shared__ short Bs[64][72];
    const int tid = threadIdx.x;
    const int wave = tid >> 6, lane = tid & 63;
    const int bm = blockIdx.x * 64, bn = blockIdx.y * 64;
    const int r = tid >> 2, qq = tid & 3;

    f32x4 acc[4];
#pragma unroll
    for (int j = 0; j < 4; j++) acc[j] = (f32x4){0.f, 0.f, 0.f, 0.f};
    const bf16x8 zz = {0,0,0,0,0,0,0,0};

    for (int kk = 0; kk < K; kk += 64) {
        {
            int gm = bm + r;
            bf16x8 a0 = zz, a1 = zz;
            if (gm < M) {
                const short* ap = A + (size_t)gm * K + kk + qq * 16;
                a0 = *(const bf16x8*)ap; a1 = *(const bf16x8*)(ap + 8);
            }
            *(bf16x8*)&As[r][qq*16] = a0; *(bf16x8*)&As[r][qq*16+8] = a1;
            int gn = bn + r;
            bf16x8 b0 = zz, b1 = zz;
            if (gn < N) {
                const short* bp = Bt + (size_t)gn * K + kk + qq * 16;
                b0 = *(const bf16x8*)bp; b1 = *(const bf16x8*)(bp + 8);
            }
            *(bf16x8*)&Bs[r][qq*16] = b0; *(bf16x8*)&Bs[r][qq*16+8] = b1;
        }
        __syncthreads();
        const int arow = (wave << 4) + (lane & 15);
        const int koff = (lane >> 4) << 3;
        bf16x8 a0 = *(const bf16x8*)&As[arow][koff];
        bf16x8 a1 = *(const bf16x8*)&As[arow][32 + koff];
#pragma unroll
        for (int j = 0; j < 4; j++) {
            const int brow = (j << 4) + (lane & 15);
            bf16x8 b0 = *(const bf16x8*)&Bs[brow][koff];
            bf16x8 b1 = *(const bf16x8*)&Bs[brow][32 + koff];
            acc[j] = MFMA(a0, b0, acc[j]);
            acc[j] = MFMA(a1, b1, acc[j]);
        }
        __syncthreads();
    }
    const int crow = bm + (wave << 4) + ((lane >> 4) << 2);
    const int ccol0 = bn + (lane & 15);
#pragma unroll
    for (int j = 0; j < 4; j++) {
        int gn = ccol0 + j * 16;
        if (gn >= N) continue;
#pragma unroll
        for (int i = 0; i < 4; i++) {
            int gm = crow + i;
            if (gm < M) C[(size_t)gm * N + gn] = acc[j][i];
        }
    }
}

// -------- depthwise causal conv (k=4) + bias + SiLU over xBC columns --------
__global__ __launch_bounds__(256) void conv_silu_kernel(const float* __restrict__ zxbcdt,
                                                        const float* __restrict__ conv_w,
                                                        const float* __restrict__ conv_b,
                                                        float* __restrict__ convout) {
    int idx = blockIdx.x * 256 + threadIdx.x;
    if (idx >= NROWS * CONVDIM) return;
    int c = idx % CONVDIM;
    int m = idx / CONVDIM;
    int t = m % SEQ;
    float acc = conv_b[c];
#pragma unroll
    for (int k = 0; k < 4; k++) {
        int tt = t - 3 + k;
        if (tt >= 0)
            acc += zxbcdt[(size_t)(m - 3 + k) * ZW + DINNER + c] * conv_w[c * 4 + k];
    }
    float s = acc / (1.f + expf(-acc));
    convout[(size_t)m * CONVDIM + c] = s;
}

// ---- fp32 recompute of dt column: la = softplus(x.w_col + bias) * -exp(A_log) ----
__global__ __launch_bounds__(256) void dt_kernel(const float* __restrict__ x,
                                                 const float* __restrict__ in_proj_w,
                                                 const float* __restrict__ dt_bias,
                                                 const float* __restrict__ A_log,
                                                 float* __restrict__ la) {
    int idx = blockIdx.x * 256 + threadIdx.x;
    if (idx >= NROWS * NHEADS) return;
    int h = idx & 15, m = idx >> 4;
    float acc = dt_bias[h];
    const float* xr = x + (size_t)m * DMODEL;
    const float* wc = in_proj_w + (DINNER + CONVDIM) + h;
#pragma unroll 4
    for (int k = 0; k < DMODEL; k++) acc += xr[k] * wc[(size_t)k * DINPROJ];
    float sp = (acc > 20.f) ? acc : log1pf(expf(acc));
    la[idx] = sp * (-expf(A_log[h]));
}

// ------------- Phase A: per-(b,chunk,head) intra-chunk + chunk state (MFMA) -------------
__global__ __launch_bounds__(256) void chunk_intra_kernel(
    const float* __restrict__ convout,
    const float* __restrict__ lab,
    const float* __restrict__ A_log,
    const float* __restrict__ D_skip,
    float* __restrict__ ybuf,
    float* __restrict__ Sbuf,
    float* __restrict__ atot,
    float* __restrict__ cumexp)
{
    const int blk = blockIdx.x;
    const int h  = blk & 15;
    const int bc = blk >> 4;
    const int c  = bc & (NCHUNK - 1);
    const int b  = bc >> 5;
    const int t0 = c * Q;
    const int len = min(Q, SEQ - t0);
    const int tid = threadIdx.x;
    const int wave = tid >> 6, lane = tid & 63;
    const size_t rowbase = (size_t)b * SEQ + t0;

    __shared__ short Ct[64][72];    // C tile [t][n]; reused as E [t][s]
    __shared__ short Bt2[64][72];   // B tile [s][n]
    __shared__ short Xt[64][72];    // x^T    [p][s]
    __shared__ short Bw[64][72];    // (w*B)^T [n][s]
    __shared__ float cum[64], sdt[64], sw[64];

    // step 1: cumsum of log-decay (wave 0)
    if (tid < 64) {
        const float nAinv = -expf(-A_log[h]);   // dt = la * nAinv
        float lav = 0.f;
        if (tid < len) lav = lab[(rowbase + tid) * NHEADS + h];
        float dtv = lav * nAinv;
        float v = lav;
#pragma unroll
        for (int off = 1; off < 64; off <<= 1) {
            float nb = __shfl_up(v, off);
            if (lane >= off) v += nb;
        }
        float last = __shfl(v, 63);
        cum[tid] = v; sdt[tid] = dtv;
        sw[tid] = expf(last - v) * dtv;
        if (tid < len) cumexp[(rowbase + tid) * NHEADS + h] = expf(v);
        if (tid == 63) atot[blk] = expf(last);
    }
    __syncthreads();

    // staging: coalesced reads, Ct/Bt2 direct, Xt/Bw transposed
    {
        const int r = tid >> 2, qq = tid & 3;
        float cf[16], bff[16], xf[16];
        if (r < len) {
            const float* row = convout + (rowbase + r) * CONVDIM;
#pragma unroll
            for (int i = 0; i < 4; i++) {
                float4 v = *(const float4*)&row[1088 + qq*16 + i*4];
                cf[4*i]=v.x; cf[4*i+1]=v.y; cf[4*i+2]=v.z; cf[4*i+3]=v.w;
                float4 w = *(const float4*)&row[1024 + qq*16 + i*4];
                bff[4*i]=w.x; bff[4*i+1]=w.y; bff[4*i+2]=w.z; bff[4*i+3]=w.w;
                float4 u = *(const float4*)&row[h*64 + qq*16 + i*4];
                xf[4*i]=u.x; xf[4*i+1]=u.y; xf[4*i+2]=u.z; xf[4*i+3]=u.w;
            }
        } else {
#pragma unroll
            for (int i = 0; i < 16; i++) { cf[i]=0.f; bff[i]=0.f; xf[i]=0.f; }
        }
        const float wsc = sw[r];
        short tmp[16];
#pragma unroll
        for (int i = 0; i < 16; i++) tmp[i] = f2bf(cf[i]);
        *(bf16x8*)&Ct[r][qq*16]   = *(const bf16x8*)&tmp[0];
        *(bf16x8*)&Ct[r][qq*16+8] = *(const bf16x8*)&tmp[8];
#pragma unroll
        for (int i = 0; i < 16; i++) tmp[i] = f2bf(bff[i]);
        *(bf16x8*)&Bt2[r][qq*16]   = *(const bf16x8*)&tmp[0];
        *(bf16x8*)&Bt2[r][qq*16+8] = *(const bf16x8*)&tmp[8];
#pragma unroll
        for (int i = 0; i < 16; i++) Xt[qq*16+i][r] = f2bf(xf[i]);
#pragma unroll
        for (int i = 0; i < 16; i++) Bw[qq*16+i][r] = f2bf(bff[i] * wsc);
    }
    __syncthreads();

    const int arow = (wave << 4) + (lane & 15);
    const int koff = (lane >> 4) << 3;
    const int trow0 = (wave << 4) + ((lane >> 4) << 2);
    const int scol = lane & 15;

    // E = C . B^T  (M=t, N=s, K=n)
    f32x4 eacc[4];
#pragma unroll
    for (int j = 0; j < 4; j++) eacc[j] = (f32x4){0.f,0.f,0.f,0.f};
    {
        bf16x8 a0 = *(const bf16x8*)&Ct[arow][koff];
        bf16x8 a1 = *(const bf16x8*)&Ct[arow][32 + koff];
#pragma unroll
        for (int j = 0; j < 4; j++) {
            const int brow = (j << 4) + (lane & 15);
            bf16x8 b0 = *(const bf16x8*)&Bt2[brow][koff];
            bf16x8 b1 = *(const bf16x8*)&Bt2[brow][32 + koff];
            eacc[j] = MFMA(a0, b0, eacc[j]);
            eacc[j] = MFMA(a1, b1, eacc[j]);
        }
    }
    // mask + decay + dt_s, convert to bf16
    short ebf[4][4];
#pragma unroll
    for (int j = 0; j < 4; j++) {
        int s = j * 16 + scol;
#pragma unroll
        for (int i = 0; i < 4; i++) {
            int t = trow0 + i;
            float val = 0.f;
            if (s <= t) val = eacc[j][i] * expf(cum[t] - cum[s]) * sdt[s];
            ebf[j][i] = f2bf(val);
        }
    }
    __syncthreads();   // all waves done reading Ct
#pragma unroll
    for (int j = 0; j < 4; j++)
#pragma unroll
        for (int i = 0; i < 4; i++)
            Ct[trow0 + i][j * 16 + scol] = ebf[j][i];
    __syncthreads();

    // Y = E @ X   (M=t, N=p, K=s); epilogue adds D*x (fp32 x from convout)
    f32x4 yacc[4];
#pragma unroll
    for (int j = 0; j < 4; j++) yacc[j] = (f32x4){0.f,0.f,0.f,0.f};
    {
        bf16x8 a0 = *(const bf16x8*)&Ct[arow][koff];
        bf16x8 a1 = *(const bf16x8*)&Ct[arow][32 + koff];
#pragma unroll
        for (int j = 0; j < 4; j++) {
            const int brow = (j << 4) + (lane & 15);
            bf16x8 b0 = *(const bf16x8*)&Xt[brow][koff];
            bf16x8 b1 = *(const bf16x8*)&Xt[brow][32 + koff];
            yacc[j] = MFMA(a0, b0, yacc[j]);
            yacc[j] = MFMA(a1, b1, yacc[j]);
        }
    }
    const float dsk = D_skip[h];
#pragma unroll
    for (int j = 0; j < 4; j++) {
        int p = j * 16 + scol;
#pragma unroll
        for (int i = 0; i < 4; i++) {
            int t = trow0 + i;
            if (t < len) {
                float xv = convout[(rowbase + t) * CONVDIM + h * 64 + p];
                ybuf[(rowbase + t) * DINNER + h * 64 + p] = yacc[j][i] + dsk * xv;
            }
        }
    }

    // S = (w x)^T B   (M=p, N=n, K=s)
    f32x4 sacc[4];
#pragma unroll
    for (int j = 0; j < 4; j++) sacc[j] = (f32x4){0.f,0.f,0.f,0.f};
    {
        bf16x8 a0 = *(const bf16x8*)&Xt[arow][koff];
        bf16x8 a1 = *(const bf16x8*)&Xt[arow][32 + koff];
#pragma unroll
        for (int j = 0; j < 4; j++) {
            const int brow = (j << 4) + (lane & 15);
            bf16x8 b0 = *(const bf16x8*)&Bw[brow][koff];
            bf16x8 b1 = *(const bf16x8*)&Bw[brow][32 + koff];
            sacc[j] = MFMA(a0, b0, sacc[j]);
            sacc[j] = MFMA(a1, b1, sacc[j]);
        }
    }
    const size_t sbase = (size_t)blk * 4096;
#pragma unroll
    for (int j = 0; j < 4; j++) {
        int n = j * 16 + scol;
#pragma unroll
        for (int i = 0; i < 4; i++) {
            int p = trow0 + i;
            Sbuf[sbase + p * 64 + n] = sacc[j][i];
        }
    }
}

// ------- Phase B: sequential scan over chunk states; Sbuf becomes Hprev -------
__global__ __launch_bounds__(256) void chunk_state_scan_kernel(
    float* __restrict__ Sbuf, const float* __restrict__ atot)
{
    const int bh = blockIdx.x;
    const int b = bh >> 4, h = bh & 15;
    const int tid = threadIdx.x;
    float H[16];
#pragma unroll
    for (int j = 0; j < 16; j++) H[j] = 0.f;
    for (int c = 0; c < NCHUNK; c++) {
        int blk = (b * NCHUNK + c) * NHEADS + h;
        size_t base = (size_t)blk * 4096;
        float at = atot[blk];
#pragma unroll
        for (int j = 0; j < 16; j++) {
            size_t off = base + tid + j * 256;
            float sv = Sbuf[off];
            Sbuf[off] = H[j];
            H[j] = at * H[j] + sv;
        }
    }
}

// ------- Phase C: Y += exp(cum_t) * C_t @ Hprev^T (MFMA) -------
__global__ __launch_bounds__(256) void chunk_inter_kernel(
    const float* __restrict__ convout,
    const float* __restrict__ Hbuf,
    const float* __restrict__ cumexp,
    float* __restrict__ ybuf)
{
    const int blk = blockIdx.x;
    const int h  = blk & 15;
    const int bc = blk >> 4;
    const int c  = bc & (NCHUNK - 1);
    const int b  = bc >> 5;
    const int t0 = c * Q;
    const int len = min(Q, SEQ - t0);
    const int tid = threadIdx.x;
    const int wave = tid >> 6, lane = tid & 63;
    const size_t rowbase = (size_t)b * SEQ + t0;

    __shared__ short Cs2[64][72];   // [t][n]
    __shared__ short Hs[64][72];    // [p][n]
    const size_t hbase = (size_t)blk * 4096;
    {
        const int r = tid >> 2, qq = tid & 3;
        short tmp[16];
        if (r < len) {
            const float* row = convout + (rowbase + r) * CONVDIM;
#pragma unroll
            for (int i = 0; i < 4; i++) {
                float4 v = *(const float4*)&row[1088 + qq*16 + i*4];
                tmp[4*i]=f2bf(v.x); tmp[4*i+1]=f2bf(v.y); tmp[4*i+2]=f2bf(v.z); tmp[4*i+3]=f2bf(v.w);
            }
        } else {
#pragma unroll
            for (int i = 0; i < 16; i++) tmp[i] = 0;
        }
        *(bf16x8*)&Cs2[r][qq*16]   = *(const bf16x8*)&tmp[0];
        *(bf16x8*)&Cs2[r][qq*16+8] = *(const bf16x8*)&tmp[8];
#pragma unroll
        for (int i = 0; i < 4; i++) {
            float4 v = *(const float4*)&Hbuf[hbase + r*64 + qq*16 + i*4];
            tmp[4*i]=f2bf(v.x); tmp[4*i+1]=f2bf(v.y); tmp[4*i+2]=f2bf(v.z); tmp[4*i+3]=f2bf(v.w);
        }
        *(bf16x8*)&Hs[r][qq*16]   = *(const bf16x8*)&tmp[0];
        *(bf16x8*)&Hs[r][qq*16+8] = *(const bf16x8*)&tmp[8];
    }
    __syncthreads();

    f32x4 yacc[4];
#pragma unroll
    for (int j = 0; j < 4; j++) yacc[j] = (f32x4){0.f,0.f,0.f,0.f};
    const int arow = (wave << 4) + (lane & 15);
    const int koff = (lane >> 4) << 3;
    bf16x8 a0 = *(const bf16x8*)&Cs2[arow][koff];
    bf16x8 a1 = *(const bf16x8*)&Cs2[arow][32 + koff];
#pragma unroll
    for (int j = 0; j < 4; j++) {
        const int brow = (j << 4) + (lane & 15);
        bf16x8 b0 = *(const bf16x8*)&Hs[brow][koff];
        bf16x8 b1 = *(const bf16x8*)&Hs[brow][32 + koff];
        yacc[j] = MFMA(a0, b0, yacc[j]);
        yacc[j] = MFMA(a1, b1, yacc[j]);
    }
    const int trow0 = (wave << 4) + ((lane >> 4) << 2);
    const int scol = lane & 15;
#pragma unroll
    for (int j = 0; j < 4; j++) {
        int p = j * 16 + scol;
#pragma unroll
        for (int i = 0; i < 4; i++) {
            int t = trow0 + i;
            if (t < len) {
                size_t off = (rowbase + t) * DINNER + h * 64 + p;
                ybuf[off] += yacc[j][i] * cumexp[(rowbase + t) * NHEADS + h];
            }
        }
    }
}

// ------------- gate with silu(z) + RMSNorm; writes bf16 copy -------------
__global__ __launch_bounds__(256) void gate_rmsnorm_kernel(float* __restrict__ y,
                                                           const float* __restrict__ zxbcdt,
                                                           const float* __restrict__ norm_w,
                                                           short* __restrict__ ybf) {
    const int m = blockIdx.x;
    const int tid = threadIdx.x;
    float vals[4];
    float ss = 0.f;
#pragma unroll
    for (int i = 0; i < 4; i++) {
        int c = tid + i * 256;
        float v = y[(size_t)m * DINNER + c];
        float z = zxbcdt[(size_t)m * ZW + c];
        float g = v * (z / (1.f + expf(-z)));
        vals[i] = g;
        ss += g * g;
    }
#pragma unroll
    for (int mask = 1; mask < 64; mask <<= 1) ss += __shfl_xor(ss, mask);
    __shared__ float red[4];
    if ((tid & 63) == 0) red[tid >> 6] = ss;
    __syncthreads();
    float tot = red[0] + red[1] + red[2] + red[3];
    float scale = rsqrtf(tot / 1024.f + 1e-5f);
#pragma unroll
    for (int i = 0; i < 4; i++) {
        int c = tid + i * 256;
        float r = vals[i] * scale * norm_w[c];
        ybf[(size_t)m * DINNER + c] = f2bf(r);
    }
}

extern "C" void kernel_launch(void* const* d_in, const int* in_sizes, int n_in,
                              void* d_out, int out_size, void* d_ws, size_t ws_size,
                              hipStream_t stream) {
    const float* x          = (const float*)d_in[0];
    const float* in_proj_w  = (const float*)d_in[1];
    const float* conv_w     = (const float*)d_in[2];
    const float* conv_b     = (const float*)d_in[3];
    const float* dt_bias    = (const float*)d_in[4];
    const float* A_log      = (const float*)d_in[5];
    const float* D_skip     = (const float*)d_in[6];
    const float* norm_w     = (const float*)d_in[7];
    const float* out_proj_w = (const float*)d_in[8];
    float* out = (float*)d_out;

    float* ws = (float*)d_ws;
    float* zxbcdt  = ws;                                    // NROWS*2176
    float* convout = zxbcdt + (size_t)NROWS * ZW;           // NROWS*1152
    float* lab     = convout + (size_t)NROWS * CONVDIM;     // NROWS*16
    float* cumexpb = lab + (size_t)NROWS * NHEADS;          // NROWS*16
    float* ybuf    = cumexpb + (size_t)NROWS * NHEADS;      // NROWS*1024
    float* Sbuf    = ybuf + (size_t)NROWS * DINNER;         // 2048*4096
    float* atotb   = Sbuf + (size_t)BATCH * NCHUNK * NHEADS * 4096;  // 2048
    short* w2t     = (short*)(atotb + 2048);                // 512*1024 bf16
    // transient aliases (dead before their hosts are written):
    short* xb  = (short*)convout;                           // NROWS*512 bf16, dead after gemm1
    short* w1t = xb + (size_t)NROWS * DMODEL;               // 2176*512 bf16, dead after gemm1
    short* ybf = (short*)Sbuf;                              // NROWS*1024 bf16, written after inter

    // prep: x -> bf16; weights -> transposed bf16 [N][K]
    convert_bf16_kernel<<<(NROWS * DMODEL / 8 + 255) / 256, 256, 0, stream>>>(x, xb, NROWS * DMODEL / 8);
    {
        dim3 g((ZW + 63) / 64, (DMODEL + 63) / 64);
        transpose_cvt_kernel<<<g, 256, 0, stream>>>(in_proj_w, w1t, DMODEL, ZW, DINPROJ);
    }
    {
        dim3 g((DMODEL + 63) / 64, (DINNER + 63) / 64);
        transpose_cvt_kernel<<<g, 256, 0, stream>>>(out_proj_w, w2t, DINNER, DMODEL, DMODEL);
    }

    // K1: zxbcdt[:, 0:2176] = x @ in_proj_w[:, 0:2176]  (bf16 MFMA)
    {
        dim3 g(128, ZW / 64);
        gemm_bf16<<<g, 256, 0, stream>>>(xb, w1t, zxbcdt, NROWS, ZW, DMODEL);
    }

    // K2: depthwise conv + silu
    conv_silu_kernel<<<(NROWS * CONVDIM + 255) / 256, 256, 0, stream>>>(zxbcdt, conv_w, conv_b, convout);

    // K2b: dt column recomputed in fp32 -> log-decay
    dt_kernel<<<(NROWS * NHEADS + 255) / 256, 256, 0, stream>>>(x, in_proj_w, dt_bias, A_log, lab);

    // K3a: intra-chunk (MFMA) + chunk states
    chunk_intra_kernel<<<BATCH * NCHUNK * NHEADS, 256, 0, stream>>>(
        convout, lab, A_log, D_skip, ybuf, Sbuf, atotb, cumexpb);

    // K3b: inter-chunk state recurrence
    chunk_state_scan_kernel<<<BATCH * NHEADS, 256, 0, stream>>>(Sbuf, atotb);

    // K3c: add inter-chunk contribution (MFMA)
    chunk_inter_kernel<<<BATCH * NCHUNK * NHEADS, 256, 0, stream>>>(
        convout, Sbuf, cumexpb, ybuf);

    // K4: gate + rmsnorm -> bf16 ybf
    gate_rmsnorm_kernel<<<NROWS, 256, 0, stream>>>(ybuf, zxbcdt, norm_w, ybf);

    // K5: out = ybf @ out_proj_w  (bf16 MFMA)
    {
        dim3 g(128, DMODEL / 64);
        gemm_bf16<<<g, 256, 0, stream>>>(ybf, w2t, out, NROWS, DMODEL, DINNER);
    }
}

// Round 5
// 219.113 us; speedup vs baseline: 9.2976x; 1.2004x over previous
//
#include <hip/hip_runtime.h>
#include <hip/hip_bf16.h>
#include <math.h>
#include <string.h>

#define BATCH   4
#define SEQ     2044
#define DMODEL  512
#define DINNER  1024
#define NHEADS  16
#define HEADDIM 64
#define DSTATE  64
#define CONVDIM 1152
#define DINPROJ 2192
#define ZW      2176          // stored width of zxbcdt (z + xBC, dt cols dropped)
#define NROWS   (BATCH*SEQ)   // 8176
#define Q       64
#define NCHUNK  32

typedef __attribute__((ext_vector_type(8))) short bf16x8;
typedef __attribute__((ext_vector_type(4))) float f32x4;

#define MFMA(a,b,c) __builtin_amdgcn_mfma_f32_16x16x32_bf16((a),(b),(c),0,0,0)

__device__ inline short f2bf(float f) {
    __hip_bfloat16 h = __float2bfloat16(f);
    short s; memcpy(&s, &h, 2); return s;
}
__device__ inline float bf2f(short s) {
    unsigned u = ((unsigned)(unsigned short)s) << 16;
    float f; memcpy(&f, &u, 4); return f;
}

// ---------------- elementwise fp32 -> bf16 convert (8/thread) ----------------
__global__ __launch_bounds__(256) void convert_bf16_kernel(const float* __restrict__ in,
                                                           short* __restrict__ out, int n8) {
    int i = blockIdx.x * 256 + threadIdx.x;
    if (i >= n8) return;
    float4 v0 = *((const float4*)in + i * 2);
    float4 v1 = *((const float4*)in + i * 2 + 1);
    short t[8];
    t[0]=f2bf(v0.x); t[1]=f2bf(v0.y); t[2]=f2bf(v0.z); t[3]=f2bf(v0.w);
    t[4]=f2bf(v1.x); t[5]=f2bf(v1.y); t[6]=f2bf(v1.z); t[7]=f2bf(v1.w);
    *((bf16x8*)out + i) = *(const bf16x8*)t;
}

// ------- transpose + convert: in fp32 [R][ldi] -> out bf16 [Cc][R] -------
__global__ __launch_bounds__(256) void transpose_cvt_kernel(const float* __restrict__ in,
                                                            short* __restrict__ out,
                                                            int R, int Cc, int ldi) {
    __shared__ float tile[64][65];
    const int bx = blockIdx.x * 64;
    const int by = blockIdx.y * 64;
    const int tid = threadIdx.x;
#pragma unroll
    for (int i = 0; i < 16; i++) {
        int idx = tid + i * 256; int r = idx >> 6, c = idx & 63;
        float v = 0.f;
        if (by + r < R && bx + c < Cc) v = in[(size_t)(by + r) * ldi + bx + c];
        tile[r][c] = v;
    }
    __syncthreads();
#pragma unroll
    for (int i = 0; i < 16; i++) {
        int idx = tid + i * 256; int c = idx >> 6, r = idx & 63;
        if (bx + c < Cc && by + r < R)
            out[(size_t)(bx + c) * R + by + r] = f2bf(tile[r][c]);
    }
}

// -------- bf16 MFMA GEMM: A[M][K] bf16, Bt[N][K] bf16 -> C[M][N] (fp32 or bf16) --------
template<bool BF16OUT>
__global__ __launch_bounds__(256) void gemm_bf16(const short* __restrict__ A,
                                                 const short* __restrict__ Bt,
                                                 void* __restrict__ Cv,
                                                 int M, int N, int K) {
    __shared__ short As[64][72];
    __shared__ short Bs[64][72];
    const int tid = threadIdx.x;
    const int wave = tid >> 6, lane = tid & 63;
    const int bm = blockIdx.x * 64, bn = blockIdx.y * 64;
    const int r = tid >> 2, qq = tid & 3;

    f32x4 acc[4];
#pragma unroll
    for (int j = 0; j < 4; j++) acc[j] = (f32x4){0.f, 0.f, 0.f, 0.f};
    const bf16x8 zz = {0,0,0,0,0,0,0,0};

    for (int kk = 0; kk < K; kk += 64) {
        {
            int gm = bm + r;
            bf16x8 a0 = zz, a1 = zz;
            if (gm < M) {
                const short* ap = A + (size_t)gm * K + kk + qq * 16;
                a0 = *(const bf16x8*)ap; a1 = *(const bf16x8*)(ap + 8);
            }
            *(bf16x8*)&As[r][qq*16] = a0; *(bf16x8*)&As[r][qq*16+8] = a1;
            int gn = bn + r;
            bf16x8 b0 = zz, b1 = zz;
            if (gn < N) {
                const short* bp = Bt + (size_t)gn * K + kk + qq * 16;
                b0 = *(const bf16x8*)bp; b1 = *(const bf16x8*)(bp + 8);
            }
            *(bf16x8*)&Bs[r][qq*16] = b0; *(bf16x8*)&Bs[r][qq*16+8] = b1;
        }
        __syncthreads();
        const int arow = (wave << 4) + (lane & 15);
        const int koff = (lane >> 4) << 3;
        bf16x8 a0 = *(const bf16x8*)&As[arow][koff];
        bf16x8 a1 = *(const bf16x8*)&As[arow][32 + koff];
#pragma unroll
        for (int j = 0; j < 4; j++) {
            const int brow = (j << 4) + (lane & 15);
            bf16x8 b0 = *(const bf16x8*)&Bs[brow][koff];
            bf16x8 b1 = *(const bf16x8*)&Bs[brow][32 + koff];
            acc[j] = MFMA(a0, b0, acc[j]);
            acc[j] = MFMA(a1, b1, acc[j]);
        }
        __syncthreads();
    }
    const int crow = bm + (wave << 4) + ((lane >> 4) << 2);
    const int ccol0 = bn + (lane & 15);
#pragma unroll
    for (int j = 0; j < 4; j++) {
        int gn = ccol0 + j * 16;
        if (gn >= N) continue;
#pragma unroll
        for (int i = 0; i < 4; i++) {
            int gm = crow + i;
            if (gm < M) {
                if (BF16OUT) ((short*)Cv)[(size_t)gm * N + gn] = f2bf(acc[j][i]);
                else         ((float*)Cv)[(size_t)gm * N + gn] = acc[j][i];
            }
        }
    }
}

// -------- depthwise causal conv (k=4) + bias + SiLU; bf16 in, bf16 out --------
// thread: one channel c, 4 consecutive t
__global__ __launch_bounds__(256) void conv_silu_kernel(const short* __restrict__ zxb,
                                                        const float* __restrict__ conv_w,
                                                        const float* __restrict__ conv_b,
                                                        short* __restrict__ convo) {
    int idx = blockIdx.x * 256 + threadIdx.x;
    if (idx >= BATCH * (SEQ/4) * CONVDIM) return;
    int c = idx % CONVDIM;
    int q = idx / CONVDIM;
    int b = q / (SEQ/4);
    int t0 = (q % (SEQ/4)) * 4;
    const size_t base = ((size_t)b * SEQ + t0) * ZW + DINNER + c;
    float4 wv = *(const float4*)&conv_w[c * 4];
    float xv[7];
#pragma unroll
    for (int i = 0; i < 7; i++) {
        int t = t0 - 3 + i;
        xv[i] = (t >= 0) ? bf2f(zxb[base + (size_t)(i - 3) * ZW]) : 0.f;
    }
    const float bias = conv_b[c];
    const size_t obase = ((size_t)b * SEQ + t0) * CONVDIM + c;
#pragma unroll
    for (int i = 0; i < 4; i++) {
        float a = bias + xv[i]*wv.x + xv[i+1]*wv.y + xv[i+2]*wv.z + xv[i+3]*wv.w;
        float s = a / (1.f + expf(-a));
        convo[obase + (size_t)i * CONVDIM] = f2bf(s);
    }
}

// ---- fp32 recompute of dt column: la = softplus(x.w_col + bias) * -exp(A_log) ----
__global__ __launch_bounds__(256) void dt_kernel(const float* __restrict__ x,
                                                 const float* __restrict__ in_proj_w,
                                                 const float* __restrict__ dt_bias,
                                                 const float* __restrict__ A_log,
                                                 float* __restrict__ la) {
    int idx = blockIdx.x * 256 + threadIdx.x;
    if (idx >= NROWS * NHEADS) return;
    int h = idx & 15, m = idx >> 4;
    float acc = dt_bias[h];
    const float* xr = x + (size_t)m * DMODEL;
    const float* wc = in_proj_w + (DINNER + CONVDIM) + h;
#pragma unroll 4
    for (int k = 0; k < DMODEL; k++) acc += xr[k] * wc[(size_t)k * DINPROJ];
    float sp = (acc > 20.f) ? acc : log1pf(expf(acc));
    la[idx] = sp * (-expf(A_log[h]));
}

// ------------- Phase A: per-(b,chunk,head) intra-chunk + chunk state (MFMA) -------------
__global__ __launch_bounds__(256) void chunk_intra_kernel(
    const short* __restrict__ convo,
    const float* __restrict__ lab,
    const float* __restrict__ A_log,
    const float* __restrict__ D_skip,
    float* __restrict__ ybuf,
    float* __restrict__ Sbuf,
    float* __restrict__ atot,
    float* __restrict__ cumexp)
{
    const int blk = blockIdx.x;
    const int h  = blk & 15;
    const int bc = blk >> 4;
    const int c  = bc & (NCHUNK - 1);
    const int b  = bc >> 5;
    const int t0 = c * Q;
    const int len = min(Q, SEQ - t0);
    const int tid = threadIdx.x;
    const int wave = tid >> 6, lane = tid & 63;
    const size_t rowbase = (size_t)b * SEQ + t0;

    __shared__ short Ct[64][72];    // C tile [t][n]; reused as E [t][s]
    __shared__ short Bt2[64][72];   // B tile [s][n]
    __shared__ short Xt[64][72];    // x^T    [p][s]
    __shared__ short Bw[64][72];    // (w*B)^T [n][s]
    __shared__ float cum[64], sdt[64], sw[64];

    if (tid < 64) {
        const float nAinv = -expf(-A_log[h]);
        float lav = 0.f;
        if (tid < len) lav = lab[(rowbase + tid) * NHEADS + h];
        float dtv = lav * nAinv;
        float v = lav;
#pragma unroll
        for (int off = 1; off < 64; off <<= 1) {
            float nb = __shfl_up(v, off);
            if (lane >= off) v += nb;
        }
        float last = __shfl(v, 63);
        cum[tid] = v; sdt[tid] = dtv;
        sw[tid] = expf(last - v) * dtv;
        if (tid < len) cumexp[(rowbase + tid) * NHEADS + h] = expf(v);
        if (tid == 63) atot[blk] = expf(last);
    }
    __syncthreads();

    // staging from bf16 convout
    {
        const int r = tid >> 2, qq = tid & 3;
        const bf16x8 zz = {0,0,0,0,0,0,0,0};
        bf16x8 c0 = zz, c1 = zz, b0 = zz, b1 = zz, x0 = zz, x1 = zz;
        if (r < len) {
            const short* row = convo + (rowbase + r) * CONVDIM;
            c0 = *(const bf16x8*)&row[1088 + qq*16];
            c1 = *(const bf16x8*)&row[1088 + qq*16 + 8];
            b0 = *(const bf16x8*)&row[1024 + qq*16];
            b1 = *(const bf16x8*)&row[1024 + qq*16 + 8];
            x0 = *(const bf16x8*)&row[h*64 + qq*16];
            x1 = *(const bf16x8*)&row[h*64 + qq*16 + 8];
        }
        *(bf16x8*)&Ct[r][qq*16]    = c0; *(bf16x8*)&Ct[r][qq*16+8]  = c1;
        *(bf16x8*)&Bt2[r][qq*16]   = b0; *(bf16x8*)&Bt2[r][qq*16+8] = b1;
        const float wsc = sw[r];
        short bs[16], xs[16];
        *(bf16x8*)&bs[0] = b0; *(bf16x8*)&bs[8] = b1;
        *(bf16x8*)&xs[0] = x0; *(bf16x8*)&xs[8] = x1;
#pragma unroll
        for (int i = 0; i < 16; i++) Xt[qq*16+i][r] = xs[i];
#pragma unroll
        for (int i = 0; i < 16; i++) Bw[qq*16+i][r] = f2bf(bf2f(bs[i]) * wsc);
    }
    __syncthreads();

    const int arow = (wave << 4) + (lane & 15);
    const int koff = (lane >> 4) << 3;
    const int trow0 = (wave << 4) + ((lane >> 4) << 2);
    const int scol = lane & 15;

    // E = C . B^T
    f32x4 eacc[4];
#pragma unroll
    for (int j = 0; j < 4; j++) eacc[j] = (f32x4){0.f,0.f,0.f,0.f};
    {
        bf16x8 a0 = *(const bf16x8*)&Ct[arow][koff];
        bf16x8 a1 = *(const bf16x8*)&Ct[arow][32 + koff];
#pragma unroll
        for (int j = 0; j < 4; j++) {
            const int brow = (j << 4) + (lane & 15);
            bf16x8 b0 = *(const bf16x8*)&Bt2[brow][koff];
            bf16x8 b1 = *(const bf16x8*)&Bt2[brow][32 + koff];
            eacc[j] = MFMA(a0, b0, eacc[j]);
            eacc[j] = MFMA(a1, b1, eacc[j]);
        }
    }
    short ebf[4][4];
#pragma unroll
    for (int j = 0; j < 4; j++) {
        int s = j * 16 + scol;
#pragma unroll
        for (int i = 0; i < 4; i++) {
            int t = trow0 + i;
            float val = 0.f;
            if (s <= t) val = eacc[j][i] * expf(cum[t] - cum[s]) * sdt[s];
            ebf[j][i] = f2bf(val);
        }
    }
    __syncthreads();
#pragma unroll
    for (int j = 0; j < 4; j++)
#pragma unroll
        for (int i = 0; i < 4; i++)
            Ct[trow0 + i][j * 16 + scol] = ebf[j][i];
    __syncthreads();

    // Y = E @ X ; epilogue adds D*x
    f32x4 yacc[4];
#pragma unroll
    for (int j = 0; j < 4; j++) yacc[j] = (f32x4){0.f,0.f,0.f,0.f};
    {
        bf16x8 a0 = *(const bf16x8*)&Ct[arow][koff];
        bf16x8 a1 = *(const bf16x8*)&Ct[arow][32 + koff];
#pragma unroll
        for (int j = 0; j < 4; j++) {
            const int brow = (j << 4) + (lane & 15);
            bf16x8 b0 = *(const bf16x8*)&Xt[brow][koff];
            bf16x8 b1 = *(const bf16x8*)&Xt[brow][32 + koff];
            yacc[j] = MFMA(a0, b0, yacc[j]);
            yacc[j] = MFMA(a1, b1, yacc[j]);
        }
    }
    const float dsk = D_skip[h];
#pragma unroll
    for (int j = 0; j < 4; j++) {
        int p = j * 16 + scol;
#pragma unroll
        for (int i = 0; i < 4; i++) {
            int t = trow0 + i;
            if (t < len) {
                float xv = bf2f(convo[(rowbase + t) * CONVDIM + h * 64 + p]);
                ybuf[(rowbase + t) * DINNER + h * 64 + p] = yacc[j][i] + dsk * xv;
            }
        }
    }

    // S = (w x)^T B
    f32x4 sacc[4];
#pragma unroll
    for (int j = 0; j < 4; j++) sacc[j] = (f32x4){0.f,0.f,0.f,0.f};
    {
        bf16x8 a0 = *(const bf16x8*)&Xt[arow][koff];
        bf16x8 a1 = *(const bf16x8*)&Xt[arow][32 + koff];
#pragma unroll
        for (int j = 0; j < 4; j++) {
            const int brow = (j << 4) + (lane & 15);
            bf16x8 b0 = *(const bf16x8*)&Bw[brow][koff];
            bf16x8 b1 = *(const bf16x8*)&Bw[brow][32 + koff];
            sacc[j] = MFMA(a0, b0, sacc[j]);
            sacc[j] = MFMA(a1, b1, sacc[j]);
        }
    }
    const size_t sbase = (size_t)blk * 4096;
#pragma unroll
    for (int j = 0; j < 4; j++) {
        int n = j * 16 + scol;
#pragma unroll
        for (int i = 0; i < 4; i++) {
            int p = trow0 + i;
            Sbuf[sbase + p * 64 + n] = sacc[j][i];
        }
    }
}

// ------- Phase B: scan over chunk states, one thread per state element -------
__global__ __launch_bounds__(256) void chunk_state_scan_kernel(
    float* __restrict__ Sbuf, const float* __restrict__ atot)
{
    int e = blockIdx.x * 256 + threadIdx.x;       // 64*4096 total
    int bh = e >> 12;
    int el = e & 4095;
    int b = bh >> 4, h = bh & 15;
    float H = 0.f;
    for (int c = 0; c < NCHUNK; c++) {
        int blk = (b * NCHUNK + c) * NHEADS + h;
        size_t off = (size_t)blk * 4096 + el;
        float sv = Sbuf[off];
        Sbuf[off] = H;
        H = atot[blk] * H + sv;
    }
}

// ------- Phase C: Y += exp(cum_t) * C_t @ Hprev^T (MFMA) -------
__global__ __launch_bounds__(256) void chunk_inter_kernel(
    const short* __restrict__ convo,
    const float* __restrict__ Hbuf,
    const float* __restrict__ cumexp,
    float* __restrict__ ybuf)
{
    const int blk = blockIdx.x;
    const int h  = blk & 15;
    const int bc = blk >> 4;
    const int c  = bc & (NCHUNK - 1);
    const int b  = bc >> 5;
    const int t0 = c * Q;
    const int len = min(Q, SEQ - t0);
    const int tid = threadIdx.x;
    const int wave = tid >> 6, lane = tid & 63;
    const size_t rowbase = (size_t)b * SEQ + t0;

    __shared__ short Cs2[64][72];
    __shared__ short Hs[64][72];
    const size_t hbase = (size_t)blk * 4096;
    {
        const int r = tid >> 2, qq = tid & 3;
        const bf16x8 zz = {0,0,0,0,0,0,0,0};
        bf16x8 c0 = zz, c1 = zz;
        if (r < len) {
            const short* row = convo + (rowbase + r) * CONVDIM;
            c0 = *(const bf16x8*)&row[1088 + qq*16];
            c1 = *(const bf16x8*)&row[1088 + qq*16 + 8];
        }
        *(bf16x8*)&Cs2[r][qq*16]   = c0;
        *(bf16x8*)&Cs2[r][qq*16+8] = c1;
        short tmp[16];
#pragma unroll
        for (int i = 0; i < 4; i++) {
            float4 v = *(const float4*)&Hbuf[hbase + r*64 + qq*16 + i*4];
            tmp[4*i]=f2bf(v.x); tmp[4*i+1]=f2bf(v.y); tmp[4*i+2]=f2bf(v.z); tmp[4*i+3]=f2bf(v.w);
        }
        *(bf16x8*)&Hs[r][qq*16]   = *(const bf16x8*)&tmp[0];
        *(bf16x8*)&Hs[r][qq*16+8] = *(const bf16x8*)&tmp[8];
    }
    __syncthreads();

    f32x4 yacc[4];
#pragma unroll
    for (int j = 0; j < 4; j++) yacc[j] = (f32x4){0.f,0.f,0.f,0.f};
    const int arow = (wave << 4) + (lane & 15);
    const int koff = (lane >> 4) << 3;
    bf16x8 a0 = *(const bf16x8*)&Cs2[arow][koff];
    bf16x8 a1 = *(const bf16x8*)&Cs2[arow][32 + koff];
#pragma unroll
    for (int j = 0; j < 4; j++) {
        const int brow = (j << 4) + (lane & 15);
        bf16x8 b0 = *(const bf16x8*)&Hs[brow][koff];
        bf16x8 b1 = *(const bf16x8*)&Hs[brow][32 + koff];
        yacc[j] = MFMA(a0, b0, yacc[j]);
        yacc[j] = MFMA(a1, b1, yacc[j]);
    }
    const int trow0 = (wave << 4) + ((lane >> 4) << 2);
    const int scol = lane & 15;
#pragma unroll
    for (int j = 0; j < 4; j++) {
        int p = j * 16 + scol;
#pragma unroll
        for (int i = 0; i < 4; i++) {
            int t = trow0 + i;
            if (t < len) {
                size_t off = (rowbase + t) * DINNER + h * 64 + p;
                ybuf[off] += yacc[j][i] * cumexp[(rowbase + t) * NHEADS + h];
            }
        }
    }
}

// ------------- gate with silu(z) + RMSNorm; writes bf16 -------------
__global__ __launch_bounds__(256) void gate_rmsnorm_kernel(const float* __restrict__ y,
                                                           const short* __restrict__ zxb,
                                                           const float* __restrict__ norm_w,
                                                           short* __restrict__ ybf) {
    const int m = blockIdx.x;
    const int tid = threadIdx.x;
    float vals[4];
    float ss = 0.f;
#pragma unroll
    for (int i = 0; i < 4; i++) {
        int c = tid + i * 256;
        float v = y[(size_t)m * DINNER + c];
        float z = bf2f(zxb[(size_t)m * ZW + c]);
        float g = v * (z / (1.f + expf(-z)));
        vals[i] = g;
        ss += g * g;
    }
#pragma unroll
    for (int mask = 1; mask < 64; mask <<= 1) ss += __shfl_xor(ss, mask);
    __shared__ float red[4];
    if ((tid & 63) == 0) red[tid >> 6] = ss;
    __syncthreads();
    float tot = red[0] + red[1] + red[2] + red[3];
    float scale = rsqrtf(tot / 1024.f + 1e-5f);
#pragma unroll
    for (int i = 0; i < 4; i++) {
        int c = tid + i * 256;
        float r = vals[i] * scale * norm_w[c];
        ybf[(size_t)m * DINNER + c] = f2bf(r);
    }
}

extern "C" void kernel_launch(void* const* d_in, const int* in_sizes, int n_in,
                              void* d_out, int out_size, void* d_ws, size_t ws_size,
                              hipStream_t stream) {
    const float* x          = (const float*)d_in[0];
    const float* in_proj_w  = (const float*)d_in[1];
    const float* conv_w     = (const float*)d_in[2];
    const float* conv_b     = (const float*)d_in[3];
    const float* dt_bias    = (const float*)d_in[4];
    const float* A_log      = (const float*)d_in[5];
    const float* D_skip     = (const float*)d_in[6];
    const float* norm_w     = (const float*)d_in[7];
    const float* out_proj_w = (const float*)d_in[8];
    float* out = (float*)d_out;

    short* zxb   = (short*)d_ws;                              // NROWS*ZW bf16
    short* convo = zxb + (size_t)NROWS * ZW;                  // NROWS*CONVDIM bf16
    float* lab   = (float*)(convo + (size_t)NROWS * CONVDIM); // NROWS*16
    float* cumexpb = lab + (size_t)NROWS * NHEADS;            // NROWS*16
    float* ybuf  = cumexpb + (size_t)NROWS * NHEADS;          // NROWS*1024
    float* Sbuf  = ybuf + (size_t)NROWS * DINNER;             // 2048*4096
    float* atotb = Sbuf + (size_t)2048 * 4096;                // 2048
    short* w2t   = (short*)(atotb + 2048);                    // 1024*512... [512][1024] bf16
    // transient aliases:
    short* xb  = convo;                                       // NROWS*512 bf16, dead after K1
    short* w1t = xb + (size_t)NROWS * DMODEL;                 // 2176*512 bf16, dead after K1
    short* ybf = (short*)Sbuf;                                // NROWS*1024 bf16, after inter

    // prep
    convert_bf16_kernel<<<(NROWS * DMODEL / 8 + 255) / 256, 256, 0, stream>>>(x, xb, NROWS * DMODEL / 8);
    {
        dim3 g((ZW + 63) / 64, (DMODEL + 63) / 64);
        transpose_cvt_kernel<<<g, 256, 0, stream>>>(in_proj_w, w1t, DMODEL, ZW, DINPROJ);
    }
    {
        dim3 g((DMODEL + 63) / 64, (DINNER + 63) / 64);
        transpose_cvt_kernel<<<g, 256, 0, stream>>>(out_proj_w, w2t, DINNER, DMODEL, DMODEL);
    }

    // K1: zxb = bf16(x @ in_proj_w[:, :2176])
    {
        dim3 g(128, ZW / 64);
        gemm_bf16<true><<<g, 256, 0, stream>>>(xb, w1t, zxb, NROWS, ZW, DMODEL);
    }

    // K2: conv + silu (bf16 in/out)
    {
        int tot = BATCH * (SEQ / 4) * CONVDIM;
        conv_silu_kernel<<<(tot + 255) / 256, 256, 0, stream>>>(zxb, conv_w, conv_b, convo);
    }

    // K2b: dt recompute fp32
    dt_kernel<<<(NROWS * NHEADS + 255) / 256, 256, 0, stream>>>(x, in_proj_w, dt_bias, A_log, lab);

    // K3a: intra-chunk + chunk states
    chunk_intra_kernel<<<BATCH * NCHUNK * NHEADS, 256, 0, stream>>>(
        convo, lab, A_log, D_skip, ybuf, Sbuf, atotb, cumexpb);

    // K3b: inter-chunk state recurrence (one thread per element)
    chunk_state_scan_kernel<<<(64 * 4096) / 256, 256, 0, stream>>>(Sbuf, atotb);

    // K3c: inter-chunk contribution
    chunk_inter_kernel<<<BATCH * NCHUNK * NHEADS, 256, 0, stream>>>(
        convo, Sbuf, cumexpb, ybuf);

    // K4: gate + rmsnorm -> bf16
    gate_rmsnorm_kernel<<<NROWS, 256, 0, stream>>>(ybuf, zxb, norm_w, ybf);

    // K5: out = ybf @ out_proj_w
    {
        dim3 g(128, DMODEL / 64);
        gemm_bf16<false><<<g, 256, 0, stream>>>(ybf, w2t, out, NROWS, DMODEL, DINNER);
    }
}

// Round 6
// 212.650 us; speedup vs baseline: 9.5802x; 1.0304x over previous
//
#include <hip/hip_runtime.h>
#include <hip/hip_bf16.h>
#include <math.h>
#include <string.h>

#define BATCH   4
#define SEQ     2044
#define DMODEL  512
#define DINNER  1024
#define NHEADS  16
#define HEADDIM 64
#define DSTATE  64
#define CONVDIM 1152
#define DINPROJ 2192
#define ZW      2176          // stored width of zxbcdt (z + xBC, dt cols dropped)
#define NROWS   (BATCH*SEQ)   // 8176
#define Q       64
#define NCHUNK  32

typedef __attribute__((ext_vector_type(8))) short bf16x8;
typedef __attribute__((ext_vector_type(4))) float f32x4;

#define MFMA(a,b,c) __builtin_amdgcn_mfma_f32_16x16x32_bf16((a),(b),(c),0,0,0)

__device__ inline short f2bf(float f) {
    __hip_bfloat16 h = __float2bfloat16(f);
    short s; memcpy(&s, &h, 2); return s;
}
__device__ inline float bf2f(short s) {
    unsigned u = ((unsigned)(unsigned short)s) << 16;
    float f; memcpy(&f, &u, 4); return f;
}

// ---------------- elementwise fp32 -> bf16 convert (8/thread) ----------------
__global__ __launch_bounds__(256) void convert_bf16_kernel(const float* __restrict__ in,
                                                           short* __restrict__ out, int n8) {
    int i = blockIdx.x * 256 + threadIdx.x;
    if (i >= n8) return;
    float4 v0 = *((const float4*)in + i * 2);
    float4 v1 = *((const float4*)in + i * 2 + 1);
    short t[8];
    t[0]=f2bf(v0.x); t[1]=f2bf(v0.y); t[2]=f2bf(v0.z); t[3]=f2bf(v0.w);
    t[4]=f2bf(v1.x); t[5]=f2bf(v1.y); t[6]=f2bf(v1.z); t[7]=f2bf(v1.w);
    *((bf16x8*)out + i) = *(const bf16x8*)t;
}

// ------- transpose + convert: in fp32 [R][ldi] -> out bf16 [Cc][R] -------
__global__ __launch_bounds__(256) void transpose_cvt_kernel(const float* __restrict__ in,
                                                            short* __restrict__ out,
                                                            int R, int Cc, int ldi) {
    __shared__ float tile[64][65];
    const int bx = blockIdx.x * 64;
    const int by = blockIdx.y * 64;
    const int tid = threadIdx.x;
#pragma unroll
    for (int i = 0; i < 16; i++) {
        int idx = tid + i * 256; int r = idx >> 6, c = idx & 63;
        float v = 0.f;
        if (by + r < R && bx + c < Cc) v = in[(size_t)(by + r) * ldi + bx + c];
        tile[r][c] = v;
    }
    __syncthreads();
#pragma unroll
    for (int i = 0; i < 16; i++) {
        int idx = tid + i * 256; int c = idx >> 6, r = idx & 63;
        if (bx + c < Cc && by + r < R)
            out[(size_t)(bx + c) * R + by + r] = f2bf(tile[r][c]);
    }
}

// -------- bf16 MFMA GEMM: A[M][K] bf16, Bt[N][K] bf16 -> C[M][N] (fp32 or bf16) --------
template<bool BF16OUT>
__global__ __launch_bounds__(256) void gemm_bf16(const short* __restrict__ A,
                                                 const short* __restrict__ Bt,
                                                 void* __restrict__ Cv,
                                                 int M, int N, int K) {
    __shared__ short As[64][72];
    __shared__ short Bs[64][72];
    const int tid = threadIdx.x;
    const int wave = tid >> 6, lane = tid & 63;
    const int bm = blockIdx.x * 64, bn = blockIdx.y * 64;
    const int r = tid >> 2, qq = tid & 3;

    f32x4 acc[4];
#pragma unroll
    for (int j = 0; j < 4; j++) acc[j] = (f32x4){0.f, 0.f, 0.f, 0.f};
    const bf16x8 zz = {0,0,0,0,0,0,0,0};

    for (int kk = 0; kk < K; kk += 64) {
        {
            int gm = bm + r;
            bf16x8 a0 = zz, a1 = zz;
            if (gm < M) {
                const short* ap = A + (size_t)gm * K + kk + qq * 16;
                a0 = *(const bf16x8*)ap; a1 = *(const bf16x8*)(ap + 8);
            }
            *(bf16x8*)&As[r][qq*16] = a0; *(bf16x8*)&As[r][qq*16+8] = a1;
            int gn = bn + r;
            bf16x8 b0 = zz, b1 = zz;
            if (gn < N) {
                const short* bp = Bt + (size_t)gn * K + kk + qq * 16;
                b0 = *(const bf16x8*)bp; b1 = *(const bf16x8*)(bp + 8);
            }
            *(bf16x8*)&Bs[r][qq*16] = b0; *(bf16x8*)&Bs[r][qq*16+8] = b1;
        }
        __syncthreads();
        const int arow = (wave << 4) + (lane & 15);
        const int koff = (lane >> 4) << 3;
        bf16x8 a0 = *(const bf16x8*)&As[arow][koff];
        bf16x8 a1 = *(const bf16x8*)&As[arow][32 + koff];
#pragma unroll
        for (int j = 0; j < 4; j++) {
            const int brow = (j << 4) + (lane & 15);
            bf16x8 b0 = *(const bf16x8*)&Bs[brow][koff];
            bf16x8 b1 = *(const bf16x8*)&Bs[brow][32 + koff];
            acc[j] = MFMA(a0, b0, acc[j]);
            acc[j] = MFMA(a1, b1, acc[j]);
        }
        __syncthreads();
    }
    const int crow = bm + (wave << 4) + ((lane >> 4) << 2);
    const int ccol0 = bn + (lane & 15);
#pragma unroll
    for (int j = 0; j < 4; j++) {
        int gn = ccol0 + j * 16;
        if (gn >= N) continue;
#pragma unroll
        for (int i = 0; i < 4; i++) {
            int gm = crow + i;
            if (gm < M) {
                if (BF16OUT) ((short*)Cv)[(size_t)gm * N + gn] = f2bf(acc[j][i]);
                else         ((float*)Cv)[(size_t)gm * N + gn] = acc[j][i];
            }
        }
    }
}

// -------- depthwise causal conv (k=4) + bias + SiLU; bf16 in, bf16 out --------
__global__ __launch_bounds__(256) void conv_silu_kernel(const short* __restrict__ zxb,
                                                        const float* __restrict__ conv_w,
                                                        const float* __restrict__ conv_b,
                                                        short* __restrict__ convo) {
    int idx = blockIdx.x * 256 + threadIdx.x;
    if (idx >= BATCH * (SEQ/4) * CONVDIM) return;
    int c = idx % CONVDIM;
    int q = idx / CONVDIM;
    int b = q / (SEQ/4);
    int t0 = (q % (SEQ/4)) * 4;
    const size_t base = ((size_t)b * SEQ + t0) * ZW + DINNER + c;
    float4 wv = *(const float4*)&conv_w[c * 4];
    float xv[7];
#pragma unroll
    for (int i = 0; i < 7; i++) {
        int t = t0 - 3 + i;
        xv[i] = (t >= 0) ? bf2f(zxb[base + (size_t)(i - 3) * ZW]) : 0.f;
    }
    const float bias = conv_b[c];
    const size_t obase = ((size_t)b * SEQ + t0) * CONVDIM + c;
#pragma unroll
    for (int i = 0; i < 4; i++) {
        float a = bias + xv[i]*wv.x + xv[i+1]*wv.y + xv[i+2]*wv.z + xv[i+3]*wv.w;
        float s = a / (1.f + expf(-a));
        convo[obase + (size_t)i * CONVDIM] = f2bf(s);
    }
}

// ---- fp32 dt: wave-per-row; lane = (h, kg). la = softplus(x.w+b) * -exp(A_log) ----
__global__ __launch_bounds__(256) void dt_kernel(const float* __restrict__ x,
                                                 const float* __restrict__ in_proj_w,
                                                 const float* __restrict__ dt_bias,
                                                 const float* __restrict__ A_log,
                                                 float* __restrict__ la) {
    const int m = blockIdx.x * 4 + (threadIdx.x >> 6);
    const int lane = threadIdx.x & 63;
    const int h = lane >> 2, kg = lane & 3;
    const float* xr = x + (size_t)m * DMODEL;
    const float* wp = in_proj_w + (DINNER + CONVDIM) + h;
    float acc = 0.f;
#pragma unroll 8
    for (int i = 0; i < 128; i++) {
        int k = kg * 128 + i;
        acc += xr[k] * wp[(size_t)k * DINPROJ];
    }
    acc += __shfl_xor(acc, 1);
    acc += __shfl_xor(acc, 2);
    if (kg == 0) {
        float v = acc + dt_bias[h];
        float sp = (v > 20.f) ? v : log1pf(expf(v));
        la[(size_t)m * NHEADS + h] = sp * (-expf(A_log[h]));
    }
}

// ------------- Phase A: per-(b,chunk,head) chunk state S = (w x)^T B -------------
__global__ __launch_bounds__(256) void chunk_state_kernel(
    const short* __restrict__ convo,
    const float* __restrict__ lab,
    const float* __restrict__ A_log,
    float* __restrict__ Sbuf,
    float* __restrict__ atot)
{
    const int blk = blockIdx.x;
    const int h  = blk & 15;
    const int bc = blk >> 4;
    const int c  = bc & (NCHUNK - 1);
    const int b  = bc >> 5;
    const int t0 = c * Q;
    const int len = min(Q, SEQ - t0);
    const int tid = threadIdx.x;
    const int wave = tid >> 6, lane = tid & 63;
    const size_t rowbase = (size_t)b * SEQ + t0;

    __shared__ short Xt[64][72];    // x^T    [p][s]
    __shared__ short Bw[64][72];    // (w*B)^T [n][s]
    __shared__ float sw[64];

    if (tid < 64) {
        const float nAinv = -expf(-A_log[h]);
        float lav = 0.f;
        if (tid < len) lav = lab[(rowbase + tid) * NHEADS + h];
        float dtv = lav * nAinv;
        float v = lav;
#pragma unroll
        for (int off = 1; off < 64; off <<= 1) {
            float nb = __shfl_up(v, off);
            if (lane >= off) v += nb;
        }
        float last = __shfl(v, 63);
        sw[tid] = expf(last - v) * dtv;
        if (tid == 63) atot[blk] = expf(last);
    }
    __syncthreads();

    {
        const int r = tid >> 2, qq = tid & 3;
        const bf16x8 zz = {0,0,0,0,0,0,0,0};
        bf16x8 b0 = zz, b1 = zz, x0 = zz, x1 = zz;
        if (r < len) {
            const short* row = convo + (rowbase + r) * CONVDIM;
            b0 = *(const bf16x8*)&row[1024 + qq*16];
            b1 = *(const bf16x8*)&row[1024 + qq*16 + 8];
            x0 = *(const bf16x8*)&row[h*64 + qq*16];
            x1 = *(const bf16x8*)&row[h*64 + qq*16 + 8];
        }
        const float wsc = sw[r];
        short bs[16], xs[16];
        *(bf16x8*)&bs[0] = b0; *(bf16x8*)&bs[8] = b1;
        *(bf16x8*)&xs[0] = x0; *(bf16x8*)&xs[8] = x1;
#pragma unroll
        for (int i = 0; i < 16; i++) Xt[qq*16+i][r] = xs[i];
#pragma unroll
        for (int i = 0; i < 16; i++) Bw[qq*16+i][r] = f2bf(bf2f(bs[i]) * wsc);
    }
    __syncthreads();

    const int arow = (wave << 4) + (lane & 15);
    const int koff = (lane >> 4) << 3;
    const int trow0 = (wave << 4) + ((lane >> 4) << 2);
    const int scol = lane & 15;

    f32x4 sacc[4];
#pragma unroll
    for (int j = 0; j < 4; j++) sacc[j] = (f32x4){0.f,0.f,0.f,0.f};
    {
        bf16x8 a0 = *(const bf16x8*)&Xt[arow][koff];
        bf16x8 a1 = *(const bf16x8*)&Xt[arow][32 + koff];
#pragma unroll
        for (int j = 0; j < 4; j++) {
            const int brow = (j << 4) + (lane & 15);
            bf16x8 b0 = *(const bf16x8*)&Bw[brow][koff];
            bf16x8 b1 = *(const bf16x8*)&Bw[brow][32 + koff];
            sacc[j] = MFMA(a0, b0, sacc[j]);
            sacc[j] = MFMA(a1, b1, sacc[j]);
        }
    }
    const size_t sbase = (size_t)blk * 4096;
#pragma unroll
    for (int j = 0; j < 4; j++) {
        int n = j * 16 + scol;
#pragma unroll
        for (int i = 0; i < 4; i++) {
            int p = trow0 + i;
            Sbuf[sbase + p * 64 + n] = sacc[j][i];
        }
    }
}

// ------- Phase B: scan over chunk states; emits bf16 Hprev per chunk -------
__global__ __launch_bounds__(256) void chunk_state_scan_kernel(
    const float* __restrict__ Sbuf, const float* __restrict__ atot,
    short* __restrict__ Hbf)
{
    int e = blockIdx.x * 256 + threadIdx.x;       // 64*4096 total
    int bh = e >> 12;
    int el = e & 4095;
    int b = bh >> 4, h = bh & 15;
    float H = 0.f;
    for (int c = 0; c < NCHUNK; c++) {
        int blk = (b * NCHUNK + c) * NHEADS + h;
        size_t off = (size_t)blk * 4096 + el;
        Hbf[off] = f2bf(H);
        H = atot[blk] * H + Sbuf[off];
    }
}

// ------- Phase C: Y = (E_masked @ X) + exp(cum_t)*(C @ Hprev^T) + D*x -> bf16 -------
__global__ __launch_bounds__(256) void chunk_yfuse_kernel(
    const short* __restrict__ convo,
    const float* __restrict__ lab,
    const float* __restrict__ A_log,
    const float* __restrict__ D_skip,
    const short* __restrict__ Hbf,
    short* __restrict__ ybf)
{
    const int blk = blockIdx.x;
    const int h  = blk & 15;
    const int bc = blk >> 4;
    const int c  = bc & (NCHUNK - 1);
    const int b  = bc >> 5;
    const int t0 = c * Q;
    const int len = min(Q, SEQ - t0);
    const int tid = threadIdx.x;
    const int wave = tid >> 6, lane = tid & 63;
    const size_t rowbase = (size_t)b * SEQ + t0;

    __shared__ short Ct[64][72];    // C [t][n]; reused as E [t][s]
    __shared__ short Bt2[64][72];   // B [s][n]
    __shared__ short Xt[64][72];    // x^T [p][s]
    __shared__ short Hs[64][72];    // Hprev [p][n]
    __shared__ float cum[64], sdt[64];

    if (tid < 64) {
        const float nAinv = -expf(-A_log[h]);
        float lav = 0.f;
        if (tid < len) lav = lab[(rowbase + tid) * NHEADS + h];
        float dtv = lav * nAinv;
        float v = lav;
#pragma unroll
        for (int off = 1; off < 64; off <<= 1) {
            float nb = __shfl_up(v, off);
            if (lane >= off) v += nb;
        }
        cum[tid] = v; sdt[tid] = dtv;
    }
    __syncthreads();

    {
        const int r = tid >> 2, qq = tid & 3;
        const bf16x8 zz = {0,0,0,0,0,0,0,0};
        bf16x8 c0 = zz, c1 = zz, b0 = zz, b1 = zz, x0 = zz, x1 = zz;
        if (r < len) {
            const short* row = convo + (rowbase + r) * CONVDIM;
            c0 = *(const bf16x8*)&row[1088 + qq*16];
            c1 = *(const bf16x8*)&row[1088 + qq*16 + 8];
            b0 = *(const bf16x8*)&row[1024 + qq*16];
            b1 = *(const bf16x8*)&row[1024 + qq*16 + 8];
            x0 = *(const bf16x8*)&row[h*64 + qq*16];
            x1 = *(const bf16x8*)&row[h*64 + qq*16 + 8];
        }
        *(bf16x8*)&Ct[r][qq*16]    = c0; *(bf16x8*)&Ct[r][qq*16+8]  = c1;
        *(bf16x8*)&Bt2[r][qq*16]   = b0; *(bf16x8*)&Bt2[r][qq*16+8] = b1;
        short xs[16];
        *(bf16x8*)&xs[0] = x0; *(bf16x8*)&xs[8] = x1;
#pragma unroll
        for (int i = 0; i < 16; i++) Xt[qq*16+i][r] = xs[i];
        // Hprev staging (bf16 direct)
        const size_t hbase = (size_t)blk * 4096;
        bf16x8 h0 = *(const bf16x8*)&Hbf[hbase + r*64 + qq*16];
        bf16x8 h1 = *(const bf16x8*)&Hbf[hbase + r*64 + qq*16 + 8];
        *(bf16x8*)&Hs[r][qq*16]   = h0;
        *(bf16x8*)&Hs[r][qq*16+8] = h1;
    }
    __syncthreads();

    const int arow = (wave << 4) + (lane & 15);
    const int koff = (lane >> 4) << 3;
    const int trow0 = (wave << 4) + ((lane >> 4) << 2);
    const int scol = lane & 15;

    // E = C.B^T and I = C.H^T (both A=Ct)
    f32x4 eacc[4], iacc[4];
#pragma unroll
    for (int j = 0; j < 4; j++) { eacc[j] = (f32x4){0.f,0.f,0.f,0.f}; iacc[j] = (f32x4){0.f,0.f,0.f,0.f}; }
    {
        bf16x8 a0 = *(const bf16x8*)&Ct[arow][koff];
        bf16x8 a1 = *(const bf16x8*)&Ct[arow][32 + koff];
#pragma unroll
        for (int j = 0; j < 4; j++) {
            const int brow = (j << 4) + (lane & 15);
            bf16x8 b0 = *(const bf16x8*)&Bt2[brow][koff];
            bf16x8 b1 = *(const bf16x8*)&Bt2[brow][32 + koff];
            eacc[j] = MFMA(a0, b0, eacc[j]);
            eacc[j] = MFMA(a1, b1, eacc[j]);
            bf16x8 h0 = *(const bf16x8*)&Hs[brow][koff];
            bf16x8 h1 = *(const bf16x8*)&Hs[brow][32 + koff];
            iacc[j] = MFMA(a0, h0, iacc[j]);
            iacc[j] = MFMA(a1, h1, iacc[j]);
        }
    }
    short ebf[4][4];
#pragma unroll
    for (int j = 0; j < 4; j++) {
        int s = j * 16 + scol;
#pragma unroll
        for (int i = 0; i < 4; i++) {
            int t = trow0 + i;
            float val = 0.f;
            if (s <= t) val = eacc[j][i] * expf(cum[t] - cum[s]) * sdt[s];
            ebf[j][i] = f2bf(val);
        }
    }
    __syncthreads();
#pragma unroll
    for (int j = 0; j < 4; j++)
#pragma unroll
        for (int i = 0; i < 4; i++)
            Ct[trow0 + i][j * 16 + scol] = ebf[j][i];
    __syncthreads();

    // Y_intra = E @ X
    f32x4 yacc[4];
#pragma unroll
    for (int j = 0; j < 4; j++) yacc[j] = (f32x4){0.f,0.f,0.f,0.f};
    {
        bf16x8 a0 = *(const bf16x8*)&Ct[arow][koff];
        bf16x8 a1 = *(const bf16x8*)&Ct[arow][32 + koff];
#pragma unroll
        for (int j = 0; j < 4; j++) {
            const int brow = (j << 4) + (lane & 15);
            bf16x8 b0 = *(const bf16x8*)&Xt[brow][koff];
            bf16x8 b1 = *(const bf16x8*)&Xt[brow][32 + koff];
            yacc[j] = MFMA(a0, b0, yacc[j]);
            yacc[j] = MFMA(a1, b1, yacc[j]);
        }
    }
    const float dsk = D_skip[h];
#pragma unroll
    for (int j = 0; j < 4; j++) {
        int p = j * 16 + scol;
#pragma unroll
        for (int i = 0; i < 4; i++) {
            int t = trow0 + i;
            if (t < len) {
                float ce = expf(cum[t]);
                float xv = bf2f(Xt[p][t]);
                float val = yacc[j][i] + ce * iacc[j][i] + dsk * xv;
                ybf[(rowbase + t) * DINNER + h * 64 + p] = f2bf(val);
            }
        }
    }
}

// ------------- gate with silu(z) + RMSNorm; in-place on bf16 y -------------
__global__ __launch_bounds__(256) void gate_rmsnorm_kernel(short* __restrict__ y,
                                                           const short* __restrict__ zxb,
                                                           const float* __restrict__ norm_w) {
    const int m = blockIdx.x;
    const int tid = threadIdx.x;
    float vals[4];
    float ss = 0.f;
#pragma unroll
    for (int i = 0; i < 4; i++) {
        int c = tid + i * 256;
        float v = bf2f(y[(size_t)m * DINNER + c]);
        float z = bf2f(zxb[(size_t)m * ZW + c]);
        float g = v * (z / (1.f + expf(-z)));
        vals[i] = g;
        ss += g * g;
    }
#pragma unroll
    for (int mask = 1; mask < 64; mask <<= 1) ss += __shfl_xor(ss, mask);
    __shared__ float red[4];
    if ((tid & 63) == 0) red[tid >> 6] = ss;
    __syncthreads();
    float tot = red[0] + red[1] + red[2] + red[3];
    float scale = rsqrtf(tot / 1024.f + 1e-5f);
#pragma unroll
    for (int i = 0; i < 4; i++) {
        int c = tid + i * 256;
        float r = vals[i] * scale * norm_w[c];
        y[(size_t)m * DINNER + c] = f2bf(r);
    }
}

extern "C" void kernel_launch(void* const* d_in, const int* in_sizes, int n_in,
                              void* d_out, int out_size, void* d_ws, size_t ws_size,
                              hipStream_t stream) {
    const float* x          = (const float*)d_in[0];
    const float* in_proj_w  = (const float*)d_in[1];
    const float* conv_w     = (const float*)d_in[2];
    const float* conv_b     = (const float*)d_in[3];
    const float* dt_bias    = (const float*)d_in[4];
    const float* A_log      = (const float*)d_in[5];
    const float* D_skip     = (const float*)d_in[6];
    const float* norm_w     = (const float*)d_in[7];
    const float* out_proj_w = (const float*)d_in[8];
    float* out = (float*)d_out;

    short* zxb   = (short*)d_ws;                              // NROWS*ZW bf16
    short* convo = zxb + (size_t)NROWS * ZW;                  // NROWS*CONVDIM bf16
    short* ybf   = convo + (size_t)NROWS * CONVDIM;           // NROWS*1024 bf16
    short* Hbf   = ybf + (size_t)NROWS * DINNER;              // 2048*4096 bf16
    float* lab   = (float*)(Hbf + (size_t)2048 * 4096);       // NROWS*16
    float* Sbuf  = lab + (size_t)NROWS * NHEADS;              // 2048*4096 f32
    float* atotb = Sbuf + (size_t)2048 * 4096;                // 2048
    short* w2t   = (short*)(atotb + 2048);                    // [512][1024] bf16
    // transient aliases (dead before hosts written):
    short* xb  = convo;                                       // NROWS*512 bf16, dead after K1
    short* w1t = xb + (size_t)NROWS * DMODEL;                 // 2176*512 bf16, dead after K1

    // prep
    convert_bf16_kernel<<<(NROWS * DMODEL / 8 + 255) / 256, 256, 0, stream>>>(x, xb, NROWS * DMODEL / 8);
    {
        dim3 g((ZW + 63) / 64, (DMODEL + 63) / 64);
        transpose_cvt_kernel<<<g, 256, 0, stream>>>(in_proj_w, w1t, DMODEL, ZW, DINPROJ);
    }
    {
        dim3 g((DMODEL + 63) / 64, (DINNER + 63) / 64);
        transpose_cvt_kernel<<<g, 256, 0, stream>>>(out_proj_w, w2t, DINNER, DMODEL, DMODEL);
    }

    // K1: zxb = bf16(x @ in_proj_w[:, :2176])
    {
        dim3 g(128, ZW / 64);
        gemm_bf16<true><<<g, 256, 0, stream>>>(xb, w1t, zxb, NROWS, ZW, DMODEL);
    }

    // K2: conv + silu (bf16 in/out)
    {
        int tot = BATCH * (SEQ / 4) * CONVDIM;
        conv_silu_kernel<<<(tot + 255) / 256, 256, 0, stream>>>(zxb, conv_w, conv_b, convo);
    }

    // K2b: dt fp32 (wave-per-row)
    dt_kernel<<<NROWS / 4, 256, 0, stream>>>(x, in_proj_w, dt_bias, A_log, lab);

    // K3a: chunk states
    chunk_state_kernel<<<BATCH * NCHUNK * NHEADS, 256, 0, stream>>>(
        convo, lab, A_log, Sbuf, atotb);

    // K3b: inter-chunk recurrence -> bf16 Hprev
    chunk_state_scan_kernel<<<(64 * 4096) / 256, 256, 0, stream>>>(Sbuf, atotb, Hbf);

    // K3c: fused intra + inter + D-skip -> bf16 y
    chunk_yfuse_kernel<<<BATCH * NCHUNK * NHEADS, 256, 0, stream>>>(
        convo, lab, A_log, D_skip, Hbf, ybf);

    // K4: gate + rmsnorm (in place, bf16)
    gate_rmsnorm_kernel<<<NROWS, 256, 0, stream>>>(ybf, zxb, norm_w);

    // K5: out = ybf @ out_proj_w
    {
        dim3 g(128, DMODEL / 64);
        gemm_bf16<false><<<g, 256, 0, stream>>>(ybf, w2t, out, NROWS, DMODEL, DINNER);
    }
}

// Round 7
// 159.341 us; speedup vs baseline: 12.7853x; 1.3346x over previous
//
#include <hip/hip_runtime.h>
#include <hip/hip_bf16.h>
#include <math.h>
#include <string.h>

#define BATCH   4
#define SEQ     2044
#define DMODEL  512
#define DINNER  1024
#define NHEADS  16
#define HEADDIM 64
#define DSTATE  64
#define CONVDIM 1152
#define DINPROJ 2192
#define ZW      2176          // bf16-stored width of zxbcdt (z + xBC); dt cols -> fp32 dtraw
#define NROWS   (BATCH*SEQ)   // 8176
#define Q       64
#define NCHUNK  32

typedef __attribute__((ext_vector_type(8))) short bf16x8;
typedef __attribute__((ext_vector_type(4))) float f32x4;

#define MFMA(a,b,c) __builtin_amdgcn_mfma_f32_16x16x32_bf16((a),(b),(c),0,0,0)

__device__ inline short f2bf(float f) {
    __hip_bfloat16 h = __float2bfloat16(f);
    short s; memcpy(&s, &h, 2); return s;
}
__device__ inline float bf2f(short s) {
    unsigned u = ((unsigned)(unsigned short)s) << 16;
    float f; memcpy(&f, &u, 4); return f;
}

// ---------------- elementwise fp32 -> bf16 convert (8/thread) ----------------
__global__ __launch_bounds__(256) void convert_bf16_kernel(const float* __restrict__ in,
                                                           short* __restrict__ out, int n8) {
    int i = blockIdx.x * 256 + threadIdx.x;
    if (i >= n8) return;
    float4 v0 = *((const float4*)in + i * 2);
    float4 v1 = *((const float4*)in + i * 2 + 1);
    short t[8];
    t[0]=f2bf(v0.x); t[1]=f2bf(v0.y); t[2]=f2bf(v0.z); t[3]=f2bf(v0.w);
    t[4]=f2bf(v1.x); t[5]=f2bf(v1.y); t[6]=f2bf(v1.z); t[7]=f2bf(v1.w);
    *((bf16x8*)out + i) = *(const bf16x8*)t;
}

// ------- transpose + convert: in fp32 [R][ldi] -> out bf16 [Cc][R] -------
__global__ __launch_bounds__(256) void transpose_cvt_kernel(const float* __restrict__ in,
                                                            short* __restrict__ out,
                                                            int R, int Cc, int ldi) {
    __shared__ float tile[64][65];
    const int bx = blockIdx.x * 64;
    const int by = blockIdx.y * 64;
    const int tid = threadIdx.x;
#pragma unroll
    for (int i = 0; i < 16; i++) {
        int idx = tid + i * 256; int r = idx >> 6, c = idx & 63;
        float v = 0.f;
        if (by + r < R && bx + c < Cc) v = in[(size_t)(by + r) * ldi + bx + c];
        tile[r][c] = v;
    }
    __syncthreads();
#pragma unroll
    for (int i = 0; i < 16; i++) {
        int idx = tid + i * 256; int c = idx >> 6, r = idx & 63;
        if (bx + c < Cc && by + r < R)
            out[(size_t)(bx + c) * R + by + r] = f2bf(tile[r][c]);
    }
}

// -------- bf16 MFMA GEMM: A[M][K] bf16, Bt[N][K] bf16 -> C[M][N] --------
// BF16OUT: C written bf16 to Cv. If dtout != nullptr, columns gn >= Nbf are
// instead written fp32 to dtout[gm*(N-Nbf) + gn-Nbf] (dt-column split).
template<bool BF16OUT>
__global__ __launch_bounds__(256) void gemm_bf16(const short* __restrict__ A,
                                                 const short* __restrict__ Bt,
                                                 void* __restrict__ Cv,
                                                 int M, int N, int K,
                                                 int Nbf, float* __restrict__ dtout) {
    __shared__ short As[64][72];
    __shared__ short Bs[64][72];
    const int tid = threadIdx.x;
    const int wave = tid >> 6, lane = tid & 63;
    const int bm = blockIdx.x * 64, bn = blockIdx.y * 64;
    const int r = tid >> 2, qq = tid & 3;

    f32x4 acc[4];
#pragma unroll
    for (int j = 0; j < 4; j++) acc[j] = (f32x4){0.f, 0.f, 0.f, 0.f};
    const bf16x8 zz = {0,0,0,0,0,0,0,0};

    for (int kk = 0; kk < K; kk += 64) {
        {
            int gm = bm + r;
            bf16x8 a0 = zz, a1 = zz;
            if (gm < M) {
                const short* ap = A + (size_t)gm * K + kk + qq * 16;
                a0 = *(const bf16x8*)ap; a1 = *(const bf16x8*)(ap + 8);
            }
            *(bf16x8*)&As[r][qq*16] = a0; *(bf16x8*)&As[r][qq*16+8] = a1;
            int gn = bn + r;
            bf16x8 b0 = zz, b1 = zz;
            if (gn < N) {
                const short* bp = Bt + (size_t)gn * K + kk + qq * 16;
                b0 = *(const bf16x8*)bp; b1 = *(const bf16x8*)(bp + 8);
            }
            *(bf16x8*)&Bs[r][qq*16] = b0; *(bf16x8*)&Bs[r][qq*16+8] = b1;
        }
        __syncthreads();
        const int arow = (wave << 4) + (lane & 15);
        const int koff = (lane >> 4) << 3;
        bf16x8 a0 = *(const bf16x8*)&As[arow][koff];
        bf16x8 a1 = *(const bf16x8*)&As[arow][32 + koff];
#pragma unroll
        for (int j = 0; j < 4; j++) {
            const int brow = (j << 4) + (lane & 15);
            bf16x8 b0 = *(const bf16x8*)&Bs[brow][koff];
            bf16x8 b1 = *(const bf16x8*)&Bs[brow][32 + koff];
            acc[j] = MFMA(a0, b0, acc[j]);
            acc[j] = MFMA(a1, b1, acc[j]);
        }
        __syncthreads();
    }
    const int crow = bm + (wave << 4) + ((lane >> 4) << 2);
    const int ccol0 = bn + (lane & 15);
    const int ndt = N - Nbf;
#pragma unroll
    for (int j = 0; j < 4; j++) {
        int gn = ccol0 + j * 16;
        if (gn >= N) continue;
#pragma unroll
        for (int i = 0; i < 4; i++) {
            int gm = crow + i;
            if (gm < M) {
                if (dtout != nullptr && gn >= Nbf) {
                    dtout[(size_t)gm * ndt + (gn - Nbf)] = acc[j][i];
                } else if (BF16OUT) {
                    ((short*)Cv)[(size_t)gm * Nbf + gn] = f2bf(acc[j][i]);
                } else {
                    ((float*)Cv)[(size_t)gm * N + gn] = acc[j][i];
                }
            }
        }
    }
}

// -------- depthwise causal conv (k=4) + bias + SiLU; bf16 in, bf16 out --------
__global__ __launch_bounds__(256) void conv_silu_kernel(const short* __restrict__ zxb,
                                                        const float* __restrict__ conv_w,
                                                        const float* __restrict__ conv_b,
                                                        short* __restrict__ convo) {
    int idx = blockIdx.x * 256 + threadIdx.x;
    if (idx >= BATCH * (SEQ/4) * CONVDIM) return;
    int c = idx % CONVDIM;
    int q = idx / CONVDIM;
    int b = q / (SEQ/4);
    int t0 = (q % (SEQ/4)) * 4;
    const size_t base = ((size_t)b * SEQ + t0) * ZW + DINNER + c;
    float4 wv = *(const float4*)&conv_w[c * 4];
    float xv[7];
#pragma unroll
    for (int i = 0; i < 7; i++) {
        int t = t0 - 3 + i;
        xv[i] = (t >= 0) ? bf2f(zxb[base + (size_t)(i - 3) * ZW]) : 0.f;
    }
    const float bias = conv_b[c];
    const size_t obase = ((size_t)b * SEQ + t0) * CONVDIM + c;
#pragma unroll
    for (int i = 0; i < 4; i++) {
        float a = bias + xv[i]*wv.x + xv[i+1]*wv.y + xv[i+2]*wv.z + xv[i+3]*wv.w;
        float s = a / (1.f + expf(-a));
        convo[obase + (size_t)i * CONVDIM] = f2bf(s);
    }
}

// ---- la = softplus(dtraw + bias) * -exp(A_log)  (elementwise over NROWS*16) ----
__global__ __launch_bounds__(256) void la_kernel(const float* __restrict__ dtraw,
                                                 const float* __restrict__ dt_bias,
                                                 const float* __restrict__ A_log,
                                                 float* __restrict__ la) {
    int idx = blockIdx.x * 256 + threadIdx.x;
    if (idx >= NROWS * NHEADS) return;
    int h = idx & 15;
    float v = dtraw[idx] + dt_bias[h];
    float sp = (v > 20.f) ? v : log1pf(expf(v));
    la[idx] = sp * (-expf(A_log[h]));
}

// ------------- Phase A: per-(b,chunk,head) chunk state S = (w x)^T B -------------
__global__ __launch_bounds__(256) void chunk_state_kernel(
    const short* __restrict__ convo,
    const float* __restrict__ lab,
    const float* __restrict__ A_log,
    float* __restrict__ Sbuf,
    float* __restrict__ atot)
{
    const int blk = blockIdx.x;
    const int h  = blk & 15;
    const int bc = blk >> 4;
    const int c  = bc & (NCHUNK - 1);
    const int b  = bc >> 5;
    const int t0 = c * Q;
    const int len = min(Q, SEQ - t0);
    const int tid = threadIdx.x;
    const int wave = tid >> 6, lane = tid & 63;
    const size_t rowbase = (size_t)b * SEQ + t0;

    __shared__ short Xt[64][72];    // x^T    [p][s]
    __shared__ short Bw[64][72];    // (w*B)^T [n][s]
    __shared__ float sw[64];

    if (tid < 64) {
        const float nAinv = -expf(-A_log[h]);
        float lav = 0.f;
        if (tid < len) lav = lab[(rowbase + tid) * NHEADS + h];
        float dtv = lav * nAinv;
        float v = lav;
#pragma unroll
        for (int off = 1; off < 64; off <<= 1) {
            float nb = __shfl_up(v, off);
            if (lane >= off) v += nb;
        }
        float last = __shfl(v, 63);
        sw[tid] = expf(last - v) * dtv;
        if (tid == 63) atot[blk] = expf(last);
    }
    __syncthreads();

    {
        const int r = tid >> 2, qq = tid & 3;
        const bf16x8 zz = {0,0,0,0,0,0,0,0};
        bf16x8 b0 = zz, b1 = zz, x0 = zz, x1 = zz;
        if (r < len) {
            const short* row = convo + (rowbase + r) * CONVDIM;
            b0 = *(const bf16x8*)&row[1024 + qq*16];
            b1 = *(const bf16x8*)&row[1024 + qq*16 + 8];
            x0 = *(const bf16x8*)&row[h*64 + qq*16];
            x1 = *(const bf16x8*)&row[h*64 + qq*16 + 8];
        }
        const float wsc = sw[r];
        short bs[16], xs[16];
        *(bf16x8*)&bs[0] = b0; *(bf16x8*)&bs[8] = b1;
        *(bf16x8*)&xs[0] = x0; *(bf16x8*)&xs[8] = x1;
#pragma unroll
        for (int i = 0; i < 16; i++) Xt[qq*16+i][r] = xs[i];
#pragma unroll
        for (int i = 0; i < 16; i++) Bw[qq*16+i][r] = f2bf(bf2f(bs[i]) * wsc);
    }
    __syncthreads();

    const int arow = (wave << 4) + (lane & 15);
    const int koff = (lane >> 4) << 3;
    const int trow0 = (wave << 4) + ((lane >> 4) << 2);
    const int scol = lane & 15;

    f32x4 sacc[4];
#pragma unroll
    for (int j = 0; j < 4; j++) sacc[j] = (f32x4){0.f,0.f,0.f,0.f};
    {
        bf16x8 a0 = *(const bf16x8*)&Xt[arow][koff];
        bf16x8 a1 = *(const bf16x8*)&Xt[arow][32 + koff];
#pragma unroll
        for (int j = 0; j < 4; j++) {
            const int brow = (j << 4) + (lane & 15);
            bf16x8 b0 = *(const bf16x8*)&Bw[brow][koff];
            bf16x8 b1 = *(const bf16x8*)&Bw[brow][32 + koff];
            sacc[j] = MFMA(a0, b0, sacc[j]);
            sacc[j] = MFMA(a1, b1, sacc[j]);
        }
    }
    const size_t sbase = (size_t)blk * 4096;
#pragma unroll
    for (int j = 0; j < 4; j++) {
        int n = j * 16 + scol;
#pragma unroll
        for (int i = 0; i < 4; i++) {
            int p = trow0 + i;
            Sbuf[sbase + p * 64 + n] = sacc[j][i];
        }
    }
}

// ------- Phase B: scan over chunk states; emits bf16 Hprev per chunk -------
__global__ __launch_bounds__(256) void chunk_state_scan_kernel(
    const float* __restrict__ Sbuf, const float* __restrict__ atot,
    short* __restrict__ Hbf)
{
    int e = blockIdx.x * 256 + threadIdx.x;       // 64*4096 total
    int bh = e >> 12;
    int el = e & 4095;
    int b = bh >> 4, h = bh & 15;
    float H = 0.f;
    for (int c = 0; c < NCHUNK; c++) {
        int blk = (b * NCHUNK + c) * NHEADS + h;
        size_t off = (size_t)blk * 4096 + el;
        Hbf[off] = f2bf(H);
        H = atot[blk] * H + Sbuf[off];
    }
}

// ------- Phase C: Y = (E_masked @ X) + exp(cum_t)*(C @ Hprev^T) + D*x -> bf16 -------
__global__ __launch_bounds__(256) void chunk_yfuse_kernel(
    const short* __restrict__ convo,
    const float* __restrict__ lab,
    const float* __restrict__ A_log,
    const float* __restrict__ D_skip,
    const short* __restrict__ Hbf,
    short* __restrict__ ybf)
{
    const int blk = blockIdx.x;
    const int h  = blk & 15;
    const int bc = blk >> 4;
    const int c  = bc & (NCHUNK - 1);
    const int b  = bc >> 5;
    const int t0 = c * Q;
    const int len = min(Q, SEQ - t0);
    const int tid = threadIdx.x;
    const int wave = tid >> 6, lane = tid & 63;
    const size_t rowbase = (size_t)b * SEQ + t0;

    __shared__ short Ct[64][72];    // C [t][n]; reused as E [t][s]
    __shared__ short Bt2[64][72];   // B [s][n]
    __shared__ short Xt[64][72];    // x^T [p][s]
    __shared__ short Hs[64][72];    // Hprev [p][n]
    __shared__ float cum[64], sdt[64];

    if (tid < 64) {
        const float nAinv = -expf(-A_log[h]);
        float lav = 0.f;
        if (tid < len) lav = lab[(rowbase + tid) * NHEADS + h];
        float dtv = lav * nAinv;
        float v = lav;
#pragma unroll
        for (int off = 1; off < 64; off <<= 1) {
            float nb = __shfl_up(v, off);
            if (lane >= off) v += nb;
        }
        cum[tid] = v; sdt[tid] = dtv;
    }
    __syncthreads();

    {
        const int r = tid >> 2, qq = tid & 3;
        const bf16x8 zz = {0,0,0,0,0,0,0,0};
        bf16x8 c0 = zz, c1 = zz, b0 = zz, b1 = zz, x0 = zz, x1 = zz;
        if (r < len) {
            const short* row = convo + (rowbase + r) * CONVDIM;
            c0 = *(const bf16x8*)&row[1088 + qq*16];
            c1 = *(const bf16x8*)&row[1088 + qq*16 + 8];
            b0 = *(const bf16x8*)&row[1024 + qq*16];
            b1 = *(const bf16x8*)&row[1024 + qq*16 + 8];
            x0 = *(const bf16x8*)&row[h*64 + qq*16];
            x1 = *(const bf16x8*)&row[h*64 + qq*16 + 8];
        }
        *(bf16x8*)&Ct[r][qq*16]    = c0; *(bf16x8*)&Ct[r][qq*16+8]  = c1;
        *(bf16x8*)&Bt2[r][qq*16]   = b0; *(bf16x8*)&Bt2[r][qq*16+8] = b1;
        short xs[16];
        *(bf16x8*)&xs[0] = x0; *(bf16x8*)&xs[8] = x1;
#pragma unroll
        for (int i = 0; i < 16; i++) Xt[qq*16+i][r] = xs[i];
        const size_t hbase = (size_t)blk * 4096;
        bf16x8 h0 = *(const bf16x8*)&Hbf[hbase + r*64 + qq*16];
        bf16x8 h1 = *(const bf16x8*)&Hbf[hbase + r*64 + qq*16 + 8];
        *(bf16x8*)&Hs[r][qq*16]   = h0;
        *(bf16x8*)&Hs[r][qq*16+8] = h1;
    }
    __syncthreads();

    const int arow = (wave << 4) + (lane & 15);
    const int koff = (lane >> 4) << 3;
    const int trow0 = (wave << 4) + ((lane >> 4) << 2);
    const int scol = lane & 15;

    // E = C.B^T and I = C.H^T (both A=Ct)
    f32x4 eacc[4], iacc[4];
#pragma unroll
    for (int j = 0; j < 4; j++) { eacc[j] = (f32x4){0.f,0.f,0.f,0.f}; iacc[j] = (f32x4){0.f,0.f,0.f,0.f}; }
    {
        bf16x8 a0 = *(const bf16x8*)&Ct[arow][koff];
        bf16x8 a1 = *(const bf16x8*)&Ct[arow][32 + koff];
#pragma unroll
        for (int j = 0; j < 4; j++) {
            const int brow = (j << 4) + (lane & 15);
            bf16x8 b0 = *(const bf16x8*)&Bt2[brow][koff];
            bf16x8 b1 = *(const bf16x8*)&Bt2[brow][32 + koff];
            eacc[j] = MFMA(a0, b0, eacc[j]);
            eacc[j] = MFMA(a1, b1, eacc[j]);
            bf16x8 h0 = *(const bf16x8*)&Hs[brow][koff];
            bf16x8 h1 = *(const bf16x8*)&Hs[brow][32 + koff];
            iacc[j] = MFMA(a0, h0, iacc[j]);
            iacc[j] = MFMA(a1, h1, iacc[j]);
        }
    }
    short ebf[4][4];
#pragma unroll
    for (int j = 0; j < 4; j++) {
        int s = j * 16 + scol;
#pragma unroll
        for (int i = 0; i < 4; i++) {
            int t = trow0 + i;
            float val = 0.f;
            if (s <= t) val = eacc[j][i] * expf(cum[t] - cum[s]) * sdt[s];
            ebf[j][i] = f2bf(val);
        }
    }
    __syncthreads();
#pragma unroll
    for (int j = 0; j < 4; j++)
#pragma unroll
        for (int i = 0; i < 4; i++)
            Ct[trow0 + i][j * 16 + scol] = ebf[j][i];
    __syncthreads();

    // Y_intra = E @ X
    f32x4 yacc[4];
#pragma unroll
    for (int j = 0; j < 4; j++) yacc[j] = (f32x4){0.f,0.f,0.f,0.f};
    {
        bf16x8 a0 = *(const bf16x8*)&Ct[arow][koff];
        bf16x8 a1 = *(const bf16x8*)&Ct[arow][32 + koff];
#pragma unroll
        for (int j = 0; j < 4; j++) {
            const int brow = (j << 4) + (lane & 15);
            bf16x8 b0 = *(const bf16x8*)&Xt[brow][koff];
            bf16x8 b1 = *(const bf16x8*)&Xt[brow][32 + koff];
            yacc[j] = MFMA(a0, b0, yacc[j]);
            yacc[j] = MFMA(a1, b1, yacc[j]);
        }
    }
    const float dsk = D_skip[h];
#pragma unroll
    for (int j = 0; j < 4; j++) {
        int p = j * 16 + scol;
#pragma unroll
        for (int i = 0; i < 4; i++) {
            int t = trow0 + i;
            if (t < len) {
                float ce = expf(cum[t]);
                float xv = bf2f(Xt[p][t]);
                float val = yacc[j][i] + ce * iacc[j][i] + dsk * xv;
                ybf[(rowbase + t) * DINNER + h * 64 + p] = f2bf(val);
            }
        }
    }
}

// ------------- gate with silu(z) + RMSNorm; in-place on bf16 y -------------
__global__ __launch_bounds__(256) void gate_rmsnorm_kernel(short* __restrict__ y,
                                                           const short* __restrict__ zxb,
                                                           const float* __restrict__ norm_w) {
    const int m = blockIdx.x;
    const int tid = threadIdx.x;
    float vals[4];
    float ss = 0.f;
#pragma unroll
    for (int i = 0; i < 4; i++) {
        int c = tid + i * 256;
        float v = bf2f(y[(size_t)m * DINNER + c]);
        float z = bf2f(zxb[(size_t)m * ZW + c]);
        float g = v * (z / (1.f + expf(-z)));
        vals[i] = g;
        ss += g * g;
    }
#pragma unroll
    for (int mask = 1; mask < 64; mask <<= 1) ss += __shfl_xor(ss, mask);
    __shared__ float red[4];
    if ((tid & 63) == 0) red[tid >> 6] = ss;
    __syncthreads();
    float tot = red[0] + red[1] + red[2] + red[3];
    float scale = rsqrtf(tot / 1024.f + 1e-5f);
#pragma unroll
    for (int i = 0; i < 4; i++) {
        int c = tid + i * 256;
        float r = vals[i] * scale * norm_w[c];
        y[(size_t)m * DINNER + c] = f2bf(r);
    }
}

extern "C" void kernel_launch(void* const* d_in, const int* in_sizes, int n_in,
                              void* d_out, int out_size, void* d_ws, size_t ws_size,
                              hipStream_t stream) {
    const float* x          = (const float*)d_in[0];
    const float* in_proj_w  = (const float*)d_in[1];
    const float* conv_w     = (const float*)d_in[2];
    const float* conv_b     = (const float*)d_in[3];
    const float* dt_bias    = (const float*)d_in[4];
    const float* A_log      = (const float*)d_in[5];
    const float* D_skip     = (const float*)d_in[6];
    const float* norm_w     = (const float*)d_in[7];
    const float* out_proj_w = (const float*)d_in[8];
    float* out = (float*)d_out;

    short* zxb   = (short*)d_ws;                              // NROWS*ZW bf16
    short* convo = zxb + (size_t)NROWS * ZW;                  // NROWS*CONVDIM bf16
    short* ybf   = convo + (size_t)NROWS * CONVDIM;           // NROWS*1024 bf16
    short* Hbf   = ybf + (size_t)NROWS * DINNER;              // 2048*4096 bf16
    float* lab   = (float*)(Hbf + (size_t)2048 * 4096);       // NROWS*16
    float* dtraw = lab + (size_t)NROWS * NHEADS;              // NROWS*16
    float* Sbuf  = dtraw + (size_t)NROWS * NHEADS;            // 2048*4096 f32
    float* atotb = Sbuf + (size_t)2048 * 4096;                // 2048
    short* w2t   = (short*)(atotb + 2048);                    // [512][1024] bf16
    // transient aliases (dead before hosts written):
    short* xb  = convo;                                       // NROWS*512 bf16, dead after K1
    short* w1t = xb + (size_t)NROWS * DMODEL;                 // 2192*512 bf16, dead after K1

    // prep
    convert_bf16_kernel<<<(NROWS * DMODEL / 8 + 255) / 256, 256, 0, stream>>>(x, xb, NROWS * DMODEL / 8);
    {
        dim3 g((DINPROJ + 63) / 64, (DMODEL + 63) / 64);
        transpose_cvt_kernel<<<g, 256, 0, stream>>>(in_proj_w, w1t, DMODEL, DINPROJ, DINPROJ);
    }
    {
        dim3 g((DMODEL + 63) / 64, (DINNER + 63) / 64);
        transpose_cvt_kernel<<<g, 256, 0, stream>>>(out_proj_w, w2t, DINNER, DMODEL, DMODEL);
    }

    // K1: full-width in_proj GEMM; cols <2176 -> bf16 zxb, cols >=2176 -> fp32 dtraw
    {
        dim3 g(128, (DINPROJ + 63) / 64);   // 128 x 35
        gemm_bf16<true><<<g, 256, 0, stream>>>(xb, w1t, zxb, NROWS, DINPROJ, DMODEL, ZW, dtraw);
    }

    // K2: conv + silu (bf16 in/out)
    {
        int tot = BATCH * (SEQ / 4) * CONVDIM;
        conv_silu_kernel<<<(tot + 255) / 256, 256, 0, stream>>>(zxb, conv_w, conv_b, convo);
    }

    // K2b: la from fp32 dtraw (elementwise)
    la_kernel<<<(NROWS * NHEADS + 255) / 256, 256, 0, stream>>>(dtraw, dt_bias, A_log, lab);

    // K3a: chunk states
    chunk_state_kernel<<<BATCH * NCHUNK * NHEADS, 256, 0, stream>>>(
        convo, lab, A_log, Sbuf, atotb);

    // K3b: inter-chunk recurrence -> bf16 Hprev
    chunk_state_scan_kernel<<<(64 * 4096) / 256, 256, 0, stream>>>(Sbuf, atotb, Hbf);

    // K3c: fused intra + inter + D-skip -> bf16 y
    chunk_yfuse_kernel<<<BATCH * NCHUNK * NHEADS, 256, 0, stream>>>(
        convo, lab, A_log, D_skip, Hbf, ybf);

    // K4: gate + rmsnorm (in place, bf16)
    gate_rmsnorm_kernel<<<NROWS, 256, 0, stream>>>(ybf, zxb, norm_w);

    // K5: out = ybf @ out_proj_w
    {
        dim3 g(128, DMODEL / 64);
        gemm_bf16<false><<<g, 256, 0, stream>>>(ybf, w2t, out, NROWS, DMODEL, DINNER, DMODEL, nullptr);
    }
}